// Round 18
// baseline (4702.192 us; speedup 1.0000x reference)
//
#include <hip/hip_runtime.h>
#include <hip/hip_cooperative_groups.h>

namespace cg = cooperative_groups;

typedef __bf16 bf16;
typedef bf16 bf16x4 __attribute__((ext_vector_type(4)));
typedef bf16 bf16x8 __attribute__((ext_vector_type(8)));
typedef float f32x4 __attribute__((ext_vector_type(4)));
typedef unsigned long u64x2 __attribute__((ext_vector_type(2)));

#define AS1 __attribute__((address_space(1)))
#define AS3 __attribute__((address_space(3)))

#define B_ 2048
#define T_ 80
#define E_ 100
#define H_ 512
#define TC_ 8               // time-chunk
#define NC_ (T_ / TC_)      // 10 chunks
#define ROWS_ 32            // batch rows per rnn block (64 blocks/task)
#define L_ 4

// SEQ is TIME-MAJOR: seq[(t*B_ + b)*H_ + h]
// U fp8 A-OPERAND layout (operand-swapped rnn: D = (h@U)^T = mfma(A=U^T, B=h)):
//   hidden-tile ht, kk-pair p -> 1024B block at (ht*8+p)*1024;
//   byte[lane*16 + half*8 + j] = U[k=(2p+half)*32+(lane>>4)*8+j][ht*16+(lane&15)] * 2^6

__device__ __forceinline__ float fast_tanh(float x) {
  float e = exp2f(x * 2.8853900817779268f);  // e^{2x}
  return 1.f - 2.f * __builtin_amdgcn_rcpf(e + 1.f);
}

__device__ __forceinline__ long pack_fp8x8(const float* f) {
  int w0 = __builtin_amdgcn_cvt_pk_fp8_f32(f[0], f[1], 0, false);
  w0 = __builtin_amdgcn_cvt_pk_fp8_f32(f[2], f[3], w0, true);
  int w1 = __builtin_amdgcn_cvt_pk_fp8_f32(f[4], f[5], 0, false);
  w1 = __builtin_amdgcn_cvt_pk_fp8_f32(f[6], f[7], w1, true);
  return (long)(((unsigned long)(unsigned)w1 << 32) | (unsigned)w0);
}

// ---- Merged weight conversion (2 launches) ----

struct WConv {
  const float* src[4];
  bf16* dst[4];
  int K[4];
  int Kp[4];
};

__global__ void convert_weight_all(WConv wc) {
  int layer = blockIdx.y;
  int idx = blockIdx.x * 256 + threadIdx.x;
  int K = wc.K[layer], Kp = wc.Kp[layer];
  if (idx >= 512 * Kp) return;
  int n = idx / Kp, k = idx - n * Kp;
  float v = (k < K) ? wc.src[layer][(long)k * 512 + n] : 0.f;
  wc.dst[layer][idx] = (bf16)v;
}

struct UConv {
  const float* src[4];
  unsigned char* dst[4];
};

__global__ void convert_u_all(UConv uc) {
  int layer = blockIdx.y;
  int idx = blockIdx.x * 256 + threadIdx.x;
  int half = idx & 1, lane = (idx >> 1) & 63, p = (idx >> 7) & 7, ht = idx >> 10;
  int q = lane >> 4;
  int k0 = (2 * p + half) * 32 + q * 8;
  int n = ht * 16 + (lane & 15);
  float f[8];
#pragma unroll
  for (int j = 0; j < 8; j++) f[j] = uc.src[layer][(long)(k0 + j) * H_ + n] * 64.f;
  *(long*)(uc.dst[layer] + (long)(ht * 8 + p) * 1024 + lane * 16 + half * 8) = pack_fp8x8(f);
}

// ---- GEMM tile device functions (256-thread sub-group, 33280B LDS slice) ----
// R16-proven single-buffer BK=64 (measured best: 46.5 us / 4-task round).
// Epilogue: LDS-staged coalesced C-store.

#define SROW_ 136  // stage row stride in bf16 (272 B)

__device__ void gemm_tile(
    const bf16* __restrict__ A, const bf16* __restrict__ Bt, bf16* __restrict__ C,
    int mtile, int ntile, int stid, char* base) {
  bf16* As0 = (bf16*)base;
  bf16* Bs0 = (bf16*)(base + 8192);
  bf16* As1 = (bf16*)(base + 16384);
  bf16* Bs1 = (bf16*)(base + 24576);
  const int K = 512;
  const int wave = stid >> 6, lane = stid & 63;
  const int l = lane & 15, q = lane >> 4;
  const long m0 = (long)mtile * 128;
  const int n0 = ntile * 128;
  const int wm = (wave >> 1) * 64, wn = (wave & 1) * 64;

  f32x4 acc[4][4] = {};

  const int e0 = stid, e1 = 256 + stid;
  const int r0 = e0 >> 2, c0 = e0 & 3;
  const int r1 = e1 >> 2, c1 = e1 & 3;
  const int s0 = c0 ^ (r0 & 3) ^ ((r0 >> 2) & 3);
  const int s1 = c1 ^ (r1 & 3) ^ ((r1 >> 2) & 3);
  const int swr = q ^ (l & 3) ^ ((l >> 2) & 3);

  const bf16* A0 = A + (m0 + r0) * K + s0 * 8;
  const bf16* A1 = A + (m0 + r1) * K + s1 * 8;
  const bf16* B0 = Bt + (long)(n0 + r0) * K + s0 * 8;
  const bf16* B1 = Bt + (long)(n0 + r1) * K + s1 * 8;
  const int w0o = (wave * 64) * 8, w1o = (256 + wave * 64) * 8;

  for (int k0 = 0; k0 < K; k0 += 64) {
    __builtin_amdgcn_global_load_lds((const AS1 void*)(A0 + k0), (AS3 void*)(As0 + w0o), 16, 0, 0);
    __builtin_amdgcn_global_load_lds((const AS1 void*)(A1 + k0), (AS3 void*)(As0 + w1o), 16, 0, 0);
    __builtin_amdgcn_global_load_lds((const AS1 void*)(B0 + k0), (AS3 void*)(Bs0 + w0o), 16, 0, 0);
    __builtin_amdgcn_global_load_lds((const AS1 void*)(B1 + k0), (AS3 void*)(Bs0 + w1o), 16, 0, 0);
    __builtin_amdgcn_global_load_lds((const AS1 void*)(A0 + k0 + 32), (AS3 void*)(As1 + w0o), 16, 0, 0);
    __builtin_amdgcn_global_load_lds((const AS1 void*)(A1 + k0 + 32), (AS3 void*)(As1 + w1o), 16, 0, 0);
    __builtin_amdgcn_global_load_lds((const AS1 void*)(B0 + k0 + 32), (AS3 void*)(Bs1 + w0o), 16, 0, 0);
    __builtin_amdgcn_global_load_lds((const AS1 void*)(B1 + k0 + 32), (AS3 void*)(Bs1 + w1o), 16, 0, 0);
    __syncthreads();
    bf16x8 af0[4], bf0[4], af1[4], bf1[4];
#pragma unroll
    for (int i = 0; i < 4; i++) {
      af0[i] = *(const bf16x8*)(As0 + (wm + i * 16 + l) * 32 + swr * 8);
      bf0[i] = *(const bf16x8*)(Bs0 + (wn + i * 16 + l) * 32 + swr * 8);
      af1[i] = *(const bf16x8*)(As1 + (wm + i * 16 + l) * 32 + swr * 8);
      bf1[i] = *(const bf16x8*)(Bs1 + (wn + i * 16 + l) * 32 + swr * 8);
    }
#pragma unroll
    for (int i = 0; i < 4; i++)
#pragma unroll
      for (int j = 0; j < 4; j++) {
        acc[i][j] = __builtin_amdgcn_mfma_f32_16x16x32_bf16(af0[i], bf0[j], acc[i][j], 0, 0, 0);
        acc[i][j] = __builtin_amdgcn_mfma_f32_16x16x32_bf16(af1[i], bf1[j], acc[i][j], 0, 0, 0);
      }
    __syncthreads();
  }
  // LDS-staged coalesced store
  bf16* stage = (bf16*)base;
#pragma unroll
  for (int ph = 0; ph < 2; ph++) {
    if (wm == ph * 64) {
#pragma unroll
      for (int i = 0; i < 4; i++)
#pragma unroll
        for (int j = 0; j < 4; j++)
#pragma unroll
          for (int r = 0; r < 4; r++)
            stage[(i * 16 + q * 4 + r) * SROW_ + wn + j * 16 + l] = (bf16)acc[i][j][r];
    }
    __syncthreads();
#pragma unroll
    for (int pass = 0; pass < 4; pass++) {
      int u = pass * 256 + stid;
      int row = u >> 4, seg = u & 15;
      bf16x8 v = *(const bf16x8*)(stage + row * SROW_ + seg * 8);
      *(bf16x8*)(C + (m0 + ph * 64 + row) * (long)H_ + n0 + seg * 8) = v;
    }
    __syncthreads();
  }
}

// layer-1 tile with fused embedding gather; mtile -> (trow, b0); K=128 (padded E)
__device__ void gemm_tile_embed(
    const int* __restrict__ tokens, const float* __restrict__ emb,
    const bf16* __restrict__ Bt, bf16* __restrict__ xwc, int t0,
    int mtile, int ntile, int stid, char* base) {
  bf16* As0 = (bf16*)base;
  bf16* Bs0 = (bf16*)(base + 8192);
  bf16* As1 = (bf16*)(base + 16384);
  bf16* Bs1 = (bf16*)(base + 24576);
  int* stok = (int*)(base + 32768);
  const int K = 128;
  const int wave = stid >> 6, lane = stid & 63;
  const int l = lane & 15, q = lane >> 4;
  const int trow = mtile >> 4;
  const int b0 = (mtile & 15) * 128;
  const int t = t0 + trow;
  const int n0 = ntile * 128;
  const int wm = (wave >> 1) * 64, wn = (wave & 1) * 64;

  if (stid < 128) stok[stid] = tokens[(b0 + stid) * T_ + t];
  __syncthreads();

  f32x4 acc[4][4] = {};

  const int e0 = stid, e1 = 256 + stid;
  const int r0 = e0 >> 2, c0 = e0 & 3;
  const int r1 = e1 >> 2, c1 = e1 & 3;
  const int s0 = c0 ^ (r0 & 3) ^ ((r0 >> 2) & 3);
  const int s1 = c1 ^ (r1 & 3) ^ ((r1 >> 2) & 3);
  const int swr = q ^ (l & 3) ^ ((l >> 2) & 3);

  const bf16* B0 = Bt + (long)(n0 + r0) * K + s0 * 8;
  const bf16* B1 = Bt + (long)(n0 + r1) * K + s1 * 8;
  const int w0o = (wave * 64) * 8, w1o = (256 + wave * 64) * 8;

  const int ar = stid >> 1, hh = stid & 1;
  const int asw = (ar & 3) ^ ((ar >> 2) & 3);
  const float* er = emb + (long)stok[ar] * E_;

  for (int k0 = 0; k0 < K; k0 += 64) {
    __builtin_amdgcn_global_load_lds((const AS1 void*)(B0 + k0), (AS3 void*)(Bs0 + w0o), 16, 0, 0);
    __builtin_amdgcn_global_load_lds((const AS1 void*)(B1 + k0), (AS3 void*)(Bs0 + w1o), 16, 0, 0);
    __builtin_amdgcn_global_load_lds((const AS1 void*)(B0 + k0 + 32), (AS3 void*)(Bs1 + w0o), 16, 0, 0);
    __builtin_amdgcn_global_load_lds((const AS1 void*)(B1 + k0 + 32), (AS3 void*)(Bs1 + w1o), 16, 0, 0);
#pragma unroll
    for (int set = 0; set < 2; set++) {
      bf16* Asx = set ? As1 : As0;
      int kb0 = k0 + set * 32;
      bf16x8 v[2];
#pragma unroll
      for (int cch = 0; cch < 2; cch++) {
        int kb = kb0 + hh * 16 + cch * 8;
#pragma unroll
        for (int j = 0; j < 8; j++) {
          int k = kb + j;
          v[cch][j] = (bf16)((k < E_) ? er[k] : 0.f);
        }
      }
      *(bf16x8*)(Asx + ar * 32 + ((2 * hh + 0) ^ asw) * 8) = v[0];
      *(bf16x8*)(Asx + ar * 32 + ((2 * hh + 1) ^ asw) * 8) = v[1];
    }
    __syncthreads();
    bf16x8 af0[4], bf0[4], af1[4], bf1[4];
#pragma unroll
    for (int i = 0; i < 4; i++) {
      af0[i] = *(const bf16x8*)(As0 + (wm + i * 16 + l) * 32 + swr * 8);
      bf0[i] = *(const bf16x8*)(Bs0 + (wn + i * 16 + l) * 32 + swr * 8);
      af1[i] = *(const bf16x8*)(As1 + (wm + i * 16 + l) * 32 + swr * 8);
      bf1[i] = *(const bf16x8*)(Bs1 + (wn + i * 16 + l) * 32 + swr * 8);
    }
#pragma unroll
    for (int i = 0; i < 4; i++)
#pragma unroll
      for (int j = 0; j < 4; j++) {
        acc[i][j] = __builtin_amdgcn_mfma_f32_16x16x32_bf16(af0[i], bf0[j], acc[i][j], 0, 0, 0);
        acc[i][j] = __builtin_amdgcn_mfma_f32_16x16x32_bf16(af1[i], bf1[j], acc[i][j], 0, 0, 0);
      }
    __syncthreads();
  }
  // LDS-staged coalesced store
  bf16* C = xwc + ((long)trow * B_ + b0) * H_;
  bf16* stage = (bf16*)base;
#pragma unroll
  for (int ph = 0; ph < 2; ph++) {
    if (wm == ph * 64) {
#pragma unroll
      for (int i = 0; i < 4; i++)
#pragma unroll
        for (int j = 0; j < 4; j++)
#pragma unroll
          for (int r = 0; r < 4; r++)
            stage[(i * 16 + q * 4 + r) * SROW_ + wn + j * 16 + l] = (bf16)acc[i][j][r];
    }
    __syncthreads();
#pragma unroll
    for (int pass = 0; pass < 4; pass++) {
      int u = pass * 256 + stid;
      int row = u >> 4, seg = u & 15;
      bf16x8 v = *(const bf16x8*)(stage + row * SROW_ + seg * 8);
      *(bf16x8*)(C + (long)(ph * 64 + row) * H_ + n0 + seg * 8) = v;
    }
    __syncthreads();
  }
}

// ---- rnn task body (1024 threads, 99840B LDS) — register-held U ----
__device__ void rnn_task(
    const bf16* __restrict__ xwc, const unsigned char* __restrict__ U8,
    const float* __restrict__ bias, int t0, int first, int blk,
    bf16* __restrict__ seq, char* smem, int tid) {
  char* hls8 = smem;                    // 2 x (32 x 520 B) fp8 h
  bf16* xws = (bf16*)(smem + 33280);    // 2 x (32 x 520) bf16: xw in / h out
  const int wave = tid >> 6, lane = tid & 63;
  const int l = lane & 15, q = lane >> 4;
  const int b0 = blk * ROWS_;

  // preload this wave's U slice into registers (hidden-tiles wave*2, wave*2+1)
  const unsigned char* Ub = U8 + (long)(wave * 2) * 8192 + lane * 16;
  u64x2 Ureg[8][2];
#pragma unroll
  for (int kk2 = 0; kk2 < 8; kk2++)
#pragma unroll
    for (int nt = 0; nt < 2; nt++)
      Ureg[kk2][nt] = *(const u64x2*)(Ub + nt * 8192 + kk2 * 1024);

  // init h_{t0-1} into hls8[0]: wave handles rows wave*2, wave*2+1
#pragma unroll
  for (int rr = 0; rr < 2; rr++) {
    int m = wave * 2 + rr;
    long pk = 0;
    if (!first) {
      const bf16* hsrc = seq + ((long)(t0 - 1) * B_ + b0 + m) * H_;
      bf16x8 v = *(const bf16x8*)(hsrc + lane * 8);
      float f[8];
#pragma unroll
      for (int j = 0; j < 8; j++) f[j] = (float)v[j] * 16.f;
      pk = pack_fp8x8(f);
    }
    *(long*)(hls8 + m * 520 + lane * 8) = pk;
  }

  float bb[2][4];
#pragma unroll
  for (int nt = 0; nt < 2; nt++)
#pragma unroll
    for (int r = 0; r < 4; r++)
      bb[nt][r] = bias[(wave * 2 + nt) * 16 + q * 4 + r];

  auto prefetch = [&](int tl2) {
    int buf = tl2 & 1;
#pragma unroll
    for (int rr = 0; rr < 2; rr++) {
      int row = wave * 2 + rr;
      __builtin_amdgcn_global_load_lds(
          (const AS1 void*)(xwc + ((long)tl2 * B_ + b0 + row) * H_ + lane * 8),
          (AS3 void*)(xws + (buf * ROWS_ + row) * 520), 16, 0, 0);
    }
  };

  prefetch(0);
  __syncthreads();  // xws buf 0 ready; hls8[0] visible

  for (int tl = 0; tl < TC_; tl++) {
    if (tl > 0) {
      const bf16* src = xws + (((tl - 1) & 1) * ROWS_) * 520;
      bf16* sp = seq + ((long)(t0 + tl - 1) * B_ + b0) * H_;
#pragma unroll
      for (int rr = 0; rr < 2; rr++) {
        int m = wave * 2 + rr;
        *(bf16x8*)(sp + (long)m * H_ + lane * 8) =
            *(const bf16x8*)(src + m * 520 + lane * 8);
      }
    }
    if (tl + 1 < TC_) prefetch(tl + 1);  // lands by this step's barrier

    const char* hb0 = hls8 + ((tl & 1) * ROWS_ + l) * 520 + q * 8;
    const char* hb1 = hb0 + 16 * 520;
    f32x4 acc[2][2] = {};
#pragma unroll
    for (int kk2 = 0; kk2 < 8; kk2++) {
      long h0a = *(const long*)(hb0 + kk2 * 64);
      long h0b = *(const long*)(hb0 + kk2 * 64 + 32);
      long h1a = *(const long*)(hb1 + kk2 * 64);
      long h1b = *(const long*)(hb1 + kk2 * 64 + 32);
#pragma unroll
      for (int nt = 0; nt < 2; nt++) {
        acc[nt][0] = __builtin_amdgcn_mfma_f32_16x16x32_fp8_fp8((long)Ureg[kk2][nt].x, h0a,
                                                                acc[nt][0], 0, 0, 0);
        acc[nt][1] = __builtin_amdgcn_mfma_f32_16x16x32_fp8_fp8((long)Ureg[kk2][nt].x, h1a,
                                                                acc[nt][1], 0, 0, 0);
        acc[nt][0] = __builtin_amdgcn_mfma_f32_16x16x32_fp8_fp8((long)Ureg[kk2][nt].y, h0b,
                                                                acc[nt][0], 0, 0, 0);
        acc[nt][1] = __builtin_amdgcn_mfma_f32_16x16x32_fp8_fp8((long)Ureg[kk2][nt].y, h1b,
                                                                acc[nt][1], 0, 0, 0);
      }
    }
#pragma unroll
    for (int nt = 0; nt < 2; nt++) {
      int hoff = (wave * 2 + nt) * 16 + q * 4;
#pragma unroll
      for (int bh = 0; bh < 2; bh++) {
        bf16* xp = xws + ((tl & 1) * ROWS_ + bh * 16 + l) * 520 + hoff;
        bf16x4 xv = *(const bf16x4*)xp;
        float hv[4];
#pragma unroll
        for (int r = 0; r < 4; r++)
          hv[r] = fast_tanh((float)xv[r] + bb[nt][r] + acc[nt][bh][r] * 0.0009765625f);
        unsigned pw = (unsigned)__builtin_amdgcn_cvt_pk_fp8_f32(
            hv[0] * 16.f, hv[1] * 16.f, 0, false);
        pw = (unsigned)__builtin_amdgcn_cvt_pk_fp8_f32(
            hv[2] * 16.f, hv[3] * 16.f, (int)pw, true);
        *(unsigned*)(hls8 + (((tl + 1) & 1) * ROWS_ + bh * 16 + l) * 520 + hoff) = pw;
        bf16x4 h4;
#pragma unroll
        for (int r = 0; r < 4; r++) h4[r] = (bf16)hv[r];
        *(bf16x4*)xp = h4;
      }
    }
    __syncthreads();  // one barrier/step
  }
  {
    const bf16* src = xws + (((TC_ - 1) & 1) * ROWS_) * 520;
    bf16* sp = seq + ((long)(t0 + TC_ - 1) * B_ + b0) * H_;
#pragma unroll
    for (int rr = 0; rr < 2; rr++) {
      int m = wave * 2 + rr;
      *(bf16x8*)(sp + (long)m * H_ + lane * 8) =
          *(const bf16x8*)(src + m * 520 + lane * 8);
    }
  }
}

struct GemmTasks {
  const bf16* A[4];
  const bf16* Bt[4];
  bf16* C[4];
  int kind[4];
  int t0[4];
};

struct RnnTasks {
  const bf16* xwc[4];
  const unsigned char* U8[4];
  const float* bias[4];
  int t0[4];
  int first[4];
};

// ---- Cooperative fused round: phase 1 gemm (all 256 blocks x 4 subgroups),
// grid sync (+ device fences for cross-XCD visibility), phase 2 rnn (n*64 blocks).
__global__ __launch_bounds__(1024, 4) void fused_round(
    GemmTasks gt, RnnTasks rt, int n, bf16* __restrict__ seq,
    const int* __restrict__ tokens, const float* __restrict__ emb) {
  __shared__ __align__(16) char smem[133120];
  const int tid = threadIdx.x;

  // phase 1: gemm tiles. sg = blockIdx*4+sub; 512 tiles/task; a block's 4
  // subgroups always share the same task & kind (barrier counts uniform).
  {
    const int sub = tid >> 8, stid = tid & 255;
    char* base = smem + sub * 33280;
    for (int u = (int)blockIdx.x * 4 + sub; u < n * 512; u += 1024) {
      int task = u >> 9, tile = u & 511;
      int mt = tile & 127, ntl = tile >> 7;
      if (gt.kind[task] == 1)
        gemm_tile_embed(tokens, emb, gt.Bt[task], gt.C[task], gt.t0[task], mt, ntl, stid, base);
      else
        gemm_tile(gt.A[task], gt.Bt[task], gt.C[task], mt, ntl, stid, base);
    }
  }

  __threadfence();           // release: xw writes device-visible
  cg::this_grid().sync();
  __threadfence();           // acquire: invalidate stale xw in reader caches
  __syncthreads();           // smem handoff gemm -> rnn

  // phase 2: rnn
  if ((int)blockIdx.x < n * 64) {
    int task = blockIdx.x >> 6, blk = blockIdx.x & 63;
    rnn_task(rt.xwc[task], rt.U8[task], rt.bias[task], rt.t0[task], rt.first[task],
             blk, seq, smem, tid);
  }
}

// ---- Fallback (serial) wrappers ----
__global__ __launch_bounds__(256) void gemm_multi(
    GemmTasks gt, const int* __restrict__ tokens, const float* __restrict__ emb) {
  __shared__ __align__(16) char smem[33280];
  const int task = blockIdx.x >> 9;
  const int tile = blockIdx.x & 511;
  const int mt = tile & 127, ntl = tile >> 7;
  if (gt.kind[task] == 1)
    gemm_tile_embed(tokens, emb, gt.Bt[task], gt.C[task], gt.t0[task], mt, ntl,
                    threadIdx.x, smem);
  else
    gemm_tile(gt.A[task], gt.Bt[task], gt.C[task], mt, ntl, threadIdx.x, smem);
}

__global__ __launch_bounds__(1024) void rnn_multi(RnnTasks rt, bf16* __restrict__ seq) {
  __shared__ __align__(16) char smem[99840];
  int task = blockIdx.x >> 6, blk = blockIdx.x & 63;
  rnn_task(rt.xwc[task], rt.U8[task], rt.bias[task], rt.t0[task], rt.first[task],
           blk, seq, smem, threadIdx.x);
}

// out[b] = sigmoid(dot(seq[(T-1)*B + b, :], Wo) + bo)
__global__ __launch_bounds__(256) void head_kernel(
    const bf16* __restrict__ seq, const float* __restrict__ Wo,
    const float* __restrict__ bo, float* __restrict__ out) {
  int wave = threadIdx.x >> 6, lane = threadIdx.x & 63;
  int row = blockIdx.x * 4 + wave;
  const bf16* p = seq + ((long)(T_ - 1) * B_ + row) * H_ + lane * 8;
  bf16x8 v = *(const bf16x8*)p;
  float s = 0.f;
#pragma unroll
  for (int i = 0; i < 8; i++) s += (float)v[i] * Wo[lane * 8 + i];
#pragma unroll
  for (int off = 32; off; off >>= 1) s += __shfl_down(s, off, 64);
  if (lane == 0) {
    float x = s + bo[0];
    out[row] = 1.f / (1.f + exp2f(-x * 1.44269504088896f));
  }
}

extern "C" void kernel_launch(void* const* d_in, const int* in_sizes, int n_in,
                              void* d_out, int out_size, void* d_ws, size_t ws_size,
                              hipStream_t stream) {
  (void)in_sizes; (void)n_in; (void)out_size;
  const int*   tokens = (const int*)d_in[0];
  const float* emb = (const float*)d_in[1];
  const float* Ws[4] = {(const float*)d_in[2], (const float*)d_in[5],
                        (const float*)d_in[8], (const float*)d_in[11]};
  const float* Us[4] = {(const float*)d_in[3], (const float*)d_in[6],
                        (const float*)d_in[9], (const float*)d_in[12]};
  const float* bs[4] = {(const float*)d_in[4], (const float*)d_in[7],
                        (const float*)d_in[10], (const float*)d_in[13]};
  const float* Wo = (const float*)d_in[14];
  const float* bo = (const float*)d_in[15];
  float* out = (float*)d_out;

  char* w = (char*)d_ws;
  const size_t SEQ_BYTES = (size_t)T_ * B_ * H_ * 2;           // 160 MB
  const size_t WEIGHTS = (512 * 128 + 3 * 512 * 512) * 2 + 4 * 512 * 512;
  const size_t XWB = (size_t)TC_ * B_ * H_ * 2;                // 16 MB
  const bool wf = ws_size >= SEQ_BYTES + WEIGHTS + 4 * XWB;    // ~227.4 MB

  bf16* SEQ = (bf16*)w;
  char* wb = w + SEQ_BYTES;
  bf16* Wt[4];
  Wt[0] = (bf16*)wb;
  Wt[1] = Wt[0] + 512 * 128;
  Wt[2] = Wt[1] + 512 * 512;
  Wt[3] = Wt[2] + 512 * 512;
  unsigned char* Up[4];
  Up[0] = (unsigned char*)(Wt[3] + 512 * 512);
  Up[1] = Up[0] + 512 * 512;
  Up[2] = Up[1] + 512 * 512;
  Up[3] = Up[2] + 512 * 512;
  char* bankbase = w + SEQ_BYTES + WEIGHTS;
  bf16* BANK[4];
  for (int i = 0; i < 4; i++) BANK[i] = (bf16*)(bankbase + (size_t)i * XWB);

  {
    WConv wc{};
    UConv uc{};
    for (int i = 0; i < 4; i++) {
      wc.src[i] = Ws[i]; wc.dst[i] = Wt[i];
      wc.K[i] = (i == 0) ? 100 : 512;
      wc.Kp[i] = (i == 0) ? 128 : 512;
      uc.src[i] = Us[i]; uc.dst[i] = Up[i];
    }
    convert_weight_all<<<dim3(1024, 4), 256, 0, stream>>>(wc);
    convert_u_all<<<dim3(128, 4), 256, 0, stream>>>(uc);
  }

  if (wf) {
    // layer-wavefront, one cooperative launch per round
    for (int r = 0; r <= NC_ - 1 + L_ - 1; r++) {
      GemmTasks gt{};
      RnnTasks rt{};
      int n = 0;
      int lmin = r - (NC_ - 1); if (lmin < 0) lmin = 0;
      int lmax = r < L_ - 1 ? r : L_ - 1;
      for (int l = lmin; l <= lmax; l++) {
        int c = r - l;
        bf16* xb = BANK[l];
        gt.A[n] = SEQ + (size_t)c * TC_ * B_ * H_;
        gt.Bt[n] = Wt[l];
        gt.C[n] = xb;
        gt.kind[n] = (l == 0) ? 1 : 2;
        gt.t0[n] = c * TC_;
        rt.xwc[n] = xb;
        rt.U8[n] = Up[l];
        rt.bias[n] = bs[l];
        rt.t0[n] = c * TC_;
        rt.first[n] = (c == 0) ? 1 : 0;
        n++;
      }
      bf16* seqp = SEQ;
      void* kargs[] = {(void*)&gt, (void*)&rt, (void*)&n, (void*)&seqp,
                       (void*)&tokens, (void*)&emb};
      hipLaunchCooperativeKernel(reinterpret_cast<const void*>(&fused_round),
                                 dim3(256), dim3(1024), kargs, 0, stream);
    }
  } else {
    // serial fallback: 2 banks
    for (int l = 0; l < L_; l++) {
      for (int c = 0; c < NC_; c++) {
        bf16* xb = BANK[c & 1];
        GemmTasks gt{};
        RnnTasks rt{};
        gt.A[0] = SEQ + (size_t)c * TC_ * B_ * H_;
        gt.Bt[0] = Wt[l];
        gt.C[0] = xb;
        gt.kind[0] = (l == 0) ? 1 : 2;
        gt.t0[0] = c * TC_;
        rt.xwc[0] = xb;
        rt.U8[0] = Up[l];
        rt.bias[0] = bs[l];
        rt.t0[0] = c * TC_;
        rt.first[0] = (c == 0) ? 1 : 0;
        gemm_multi<<<512, 256, 0, stream>>>(gt, tokens, emb);
        rnn_multi<<<64, 1024, 0, stream>>>(rt, SEQ);
      }
    }
  }

  head_kernel<<<B_ / 4, 256, 0, stream>>>(SEQ, Wo, bo, out);
}

// Round 19
// 4681.667 us; speedup vs baseline: 1.0044x; 1.0044x over previous
//
#include <hip/hip_runtime.h>
#include <hip/hip_cooperative_groups.h>

namespace cg = cooperative_groups;

typedef __bf16 bf16;
typedef bf16 bf16x4 __attribute__((ext_vector_type(4)));
typedef bf16 bf16x8 __attribute__((ext_vector_type(8)));
typedef float f32x4 __attribute__((ext_vector_type(4)));
typedef unsigned long u64x2 __attribute__((ext_vector_type(2)));

#define AS1 __attribute__((address_space(1)))
#define AS3 __attribute__((address_space(3)))

#define B_ 2048
#define T_ 80
#define E_ 100
#define H_ 512
#define TC_ 8               // time-chunk
#define NC_ (T_ / TC_)      // 10 chunks
#define ROWS_ 32            // batch rows per rnn block (64 blocks/task)
#define L_ 4

// SEQ is TIME-MAJOR: seq[(t*B_ + b)*H_ + h]
// U fp8 A-OPERAND layout (operand-swapped rnn: D = (h@U)^T = mfma(A=U^T, B=h)):
//   hidden-tile ht, kk-pair p -> 1024B block at (ht*8+p)*1024;
//   byte[lane*16 + half*8 + j] = U[k=(2p+half)*32+(lane>>4)*8+j][ht*16+(lane&15)] * 2^6

__device__ __forceinline__ float fast_tanh(float x) {
  float e = exp2f(x * 2.8853900817779268f);  // e^{2x}
  return 1.f - 2.f * __builtin_amdgcn_rcpf(e + 1.f);
}

__device__ __forceinline__ long pack_fp8x8(const float* f) {
  int w0 = __builtin_amdgcn_cvt_pk_fp8_f32(f[0], f[1], 0, false);
  w0 = __builtin_amdgcn_cvt_pk_fp8_f32(f[2], f[3], w0, true);
  int w1 = __builtin_amdgcn_cvt_pk_fp8_f32(f[4], f[5], 0, false);
  w1 = __builtin_amdgcn_cvt_pk_fp8_f32(f[6], f[7], w1, true);
  return (long)(((unsigned long)(unsigned)w1 << 32) | (unsigned)w0);
}

// ---- Merged weight conversion (2 launches) ----

struct WConv {
  const float* src[4];
  bf16* dst[4];
  int K[4];
  int Kp[4];
};

__global__ void convert_weight_all(WConv wc) {
  int layer = blockIdx.y;
  int idx = blockIdx.x * 256 + threadIdx.x;
  int K = wc.K[layer], Kp = wc.Kp[layer];
  if (idx >= 512 * Kp) return;
  int n = idx / Kp, k = idx - n * Kp;
  float v = (k < K) ? wc.src[layer][(long)k * 512 + n] : 0.f;
  wc.dst[layer][idx] = (bf16)v;
}

struct UConv {
  const float* src[4];
  unsigned char* dst[4];
};

__global__ void convert_u_all(UConv uc) {
  int layer = blockIdx.y;
  int idx = blockIdx.x * 256 + threadIdx.x;
  int half = idx & 1, lane = (idx >> 1) & 63, p = (idx >> 7) & 7, ht = idx >> 10;
  int q = lane >> 4;
  int k0 = (2 * p + half) * 32 + q * 8;
  int n = ht * 16 + (lane & 15);
  float f[8];
#pragma unroll
  for (int j = 0; j < 8; j++) f[j] = uc.src[layer][(long)(k0 + j) * H_ + n] * 64.f;
  *(long*)(uc.dst[layer] + (long)(ht * 8 + p) * 1024 + lane * 16 + half * 8) = pack_fp8x8(f);
}

// ---- GEMM tile device functions (256-thread sub-group, 33280B LDS slice) ----

#define SROW_ 136  // stage row stride in bf16 (272 B)

__device__ void gemm_tile(
    const bf16* __restrict__ A, const bf16* __restrict__ Bt, bf16* __restrict__ C,
    int mtile, int ntile, int stid, char* base) {
  bf16* As0 = (bf16*)base;
  bf16* Bs0 = (bf16*)(base + 8192);
  bf16* As1 = (bf16*)(base + 16384);
  bf16* Bs1 = (bf16*)(base + 24576);
  const int K = 512;
  const int wave = stid >> 6, lane = stid & 63;
  const int l = lane & 15, q = lane >> 4;
  const long m0 = (long)mtile * 128;
  const int n0 = ntile * 128;
  const int wm = (wave >> 1) * 64, wn = (wave & 1) * 64;

  f32x4 acc[4][4] = {};

  const int e0 = stid, e1 = 256 + stid;
  const int r0 = e0 >> 2, c0 = e0 & 3;
  const int r1 = e1 >> 2, c1 = e1 & 3;
  const int s0 = c0 ^ (r0 & 3) ^ ((r0 >> 2) & 3);
  const int s1 = c1 ^ (r1 & 3) ^ ((r1 >> 2) & 3);
  const int swr = q ^ (l & 3) ^ ((l >> 2) & 3);

  const bf16* A0 = A + (m0 + r0) * K + s0 * 8;
  const bf16* A1 = A + (m0 + r1) * K + s1 * 8;
  const bf16* B0 = Bt + (long)(n0 + r0) * K + s0 * 8;
  const bf16* B1 = Bt + (long)(n0 + r1) * K + s1 * 8;
  const int w0o = (wave * 64) * 8, w1o = (256 + wave * 64) * 8;

  for (int k0 = 0; k0 < K; k0 += 64) {
    __builtin_amdgcn_global_load_lds((const AS1 void*)(A0 + k0), (AS3 void*)(As0 + w0o), 16, 0, 0);
    __builtin_amdgcn_global_load_lds((const AS1 void*)(A1 + k0), (AS3 void*)(As0 + w1o), 16, 0, 0);
    __builtin_amdgcn_global_load_lds((const AS1 void*)(B0 + k0), (AS3 void*)(Bs0 + w0o), 16, 0, 0);
    __builtin_amdgcn_global_load_lds((const AS1 void*)(B1 + k0), (AS3 void*)(Bs0 + w1o), 16, 0, 0);
    __builtin_amdgcn_global_load_lds((const AS1 void*)(A0 + k0 + 32), (AS3 void*)(As1 + w0o), 16, 0, 0);
    __builtin_amdgcn_global_load_lds((const AS1 void*)(A1 + k0 + 32), (AS3 void*)(As1 + w1o), 16, 0, 0);
    __builtin_amdgcn_global_load_lds((const AS1 void*)(B0 + k0 + 32), (AS3 void*)(Bs1 + w0o), 16, 0, 0);
    __builtin_amdgcn_global_load_lds((const AS1 void*)(B1 + k0 + 32), (AS3 void*)(Bs1 + w1o), 16, 0, 0);
    __syncthreads();
    bf16x8 af0[4], bf0[4], af1[4], bf1[4];
#pragma unroll
    for (int i = 0; i < 4; i++) {
      af0[i] = *(const bf16x8*)(As0 + (wm + i * 16 + l) * 32 + swr * 8);
      bf0[i] = *(const bf16x8*)(Bs0 + (wn + i * 16 + l) * 32 + swr * 8);
      af1[i] = *(const bf16x8*)(As1 + (wm + i * 16 + l) * 32 + swr * 8);
      bf1[i] = *(const bf16x8*)(Bs1 + (wn + i * 16 + l) * 32 + swr * 8);
    }
#pragma unroll
    for (int i = 0; i < 4; i++)
#pragma unroll
      for (int j = 0; j < 4; j++) {
        acc[i][j] = __builtin_amdgcn_mfma_f32_16x16x32_bf16(af0[i], bf0[j], acc[i][j], 0, 0, 0);
        acc[i][j] = __builtin_amdgcn_mfma_f32_16x16x32_bf16(af1[i], bf1[j], acc[i][j], 0, 0, 0);
      }
    __syncthreads();
  }
  // LDS-staged coalesced store
  bf16* stage = (bf16*)base;
#pragma unroll
  for (int ph = 0; ph < 2; ph++) {
    if (wm == ph * 64) {
#pragma unroll
      for (int i = 0; i < 4; i++)
#pragma unroll
        for (int j = 0; j < 4; j++)
#pragma unroll
          for (int r = 0; r < 4; r++)
            stage[(i * 16 + q * 4 + r) * SROW_ + wn + j * 16 + l] = (bf16)acc[i][j][r];
    }
    __syncthreads();
#pragma unroll
    for (int pass = 0; pass < 4; pass++) {
      int u = pass * 256 + stid;
      int row = u >> 4, seg = u & 15;
      bf16x8 v = *(const bf16x8*)(stage + row * SROW_ + seg * 8);
      *(bf16x8*)(C + (m0 + ph * 64 + row) * (long)H_ + n0 + seg * 8) = v;
    }
    __syncthreads();
  }
}

// layer-1 tile with fused embedding gather; mtile -> (trow, b0); K=128 (padded E)
__device__ void gemm_tile_embed(
    const int* __restrict__ tokens, const float* __restrict__ emb,
    const bf16* __restrict__ Bt, bf16* __restrict__ xwc, int t0,
    int mtile, int ntile, int stid, char* base) {
  bf16* As0 = (bf16*)base;
  bf16* Bs0 = (bf16*)(base + 8192);
  bf16* As1 = (bf16*)(base + 16384);
  bf16* Bs1 = (bf16*)(base + 24576);
  int* stok = (int*)(base + 32768);
  const int K = 128;
  const int wave = stid >> 6, lane = stid & 63;
  const int l = lane & 15, q = lane >> 4;
  const int trow = mtile >> 4;
  const int b0 = (mtile & 15) * 128;
  const int t = t0 + trow;
  const int n0 = ntile * 128;
  const int wm = (wave >> 1) * 64, wn = (wave & 1) * 64;

  if (stid < 128) stok[stid] = tokens[(b0 + stid) * T_ + t];
  __syncthreads();

  f32x4 acc[4][4] = {};

  const int e0 = stid, e1 = 256 + stid;
  const int r0 = e0 >> 2, c0 = e0 & 3;
  const int r1 = e1 >> 2, c1 = e1 & 3;
  const int s0 = c0 ^ (r0 & 3) ^ ((r0 >> 2) & 3);
  const int s1 = c1 ^ (r1 & 3) ^ ((r1 >> 2) & 3);
  const int swr = q ^ (l & 3) ^ ((l >> 2) & 3);

  const bf16* B0 = Bt + (long)(n0 + r0) * K + s0 * 8;
  const bf16* B1 = Bt + (long)(n0 + r1) * K + s1 * 8;
  const int w0o = (wave * 64) * 8, w1o = (256 + wave * 64) * 8;

  const int ar = stid >> 1, hh = stid & 1;
  const int asw = (ar & 3) ^ ((ar >> 2) & 3);
  const float* er = emb + (long)stok[ar] * E_;

  for (int k0 = 0; k0 < K; k0 += 64) {
    __builtin_amdgcn_global_load_lds((const AS1 void*)(B0 + k0), (AS3 void*)(Bs0 + w0o), 16, 0, 0);
    __builtin_amdgcn_global_load_lds((const AS1 void*)(B1 + k0), (AS3 void*)(Bs0 + w1o), 16, 0, 0);
    __builtin_amdgcn_global_load_lds((const AS1 void*)(B0 + k0 + 32), (AS3 void*)(Bs1 + w0o), 16, 0, 0);
    __builtin_amdgcn_global_load_lds((const AS1 void*)(B1 + k0 + 32), (AS3 void*)(Bs1 + w1o), 16, 0, 0);
#pragma unroll
    for (int set = 0; set < 2; set++) {
      bf16* Asx = set ? As1 : As0;
      int kb0 = k0 + set * 32;
      bf16x8 v[2];
#pragma unroll
      for (int cch = 0; cch < 2; cch++) {
        int kb = kb0 + hh * 16 + cch * 8;
#pragma unroll
        for (int j = 0; j < 8; j++) {
          int k = kb + j;
          v[cch][j] = (bf16)((k < E_) ? er[k] : 0.f);
        }
      }
      *(bf16x8*)(Asx + ar * 32 + ((2 * hh + 0) ^ asw) * 8) = v[0];
      *(bf16x8*)(Asx + ar * 32 + ((2 * hh + 1) ^ asw) * 8) = v[1];
    }
    __syncthreads();
    bf16x8 af0[4], bf0[4], af1[4], bf1[4];
#pragma unroll
    for (int i = 0; i < 4; i++) {
      af0[i] = *(const bf16x8*)(As0 + (wm + i * 16 + l) * 32 + swr * 8);
      bf0[i] = *(const bf16x8*)(Bs0 + (wn + i * 16 + l) * 32 + swr * 8);
      af1[i] = *(const bf16x8*)(As1 + (wm + i * 16 + l) * 32 + swr * 8);
      bf1[i] = *(const bf16x8*)(Bs1 + (wn + i * 16 + l) * 32 + swr * 8);
    }
#pragma unroll
    for (int i = 0; i < 4; i++)
#pragma unroll
      for (int j = 0; j < 4; j++) {
        acc[i][j] = __builtin_amdgcn_mfma_f32_16x16x32_bf16(af0[i], bf0[j], acc[i][j], 0, 0, 0);
        acc[i][j] = __builtin_amdgcn_mfma_f32_16x16x32_bf16(af1[i], bf1[j], acc[i][j], 0, 0, 0);
      }
    __syncthreads();
  }
  // LDS-staged coalesced store
  bf16* C = xwc + ((long)trow * B_ + b0) * H_;
  bf16* stage = (bf16*)base;
#pragma unroll
  for (int ph = 0; ph < 2; ph++) {
    if (wm == ph * 64) {
#pragma unroll
      for (int i = 0; i < 4; i++)
#pragma unroll
        for (int j = 0; j < 4; j++)
#pragma unroll
          for (int r = 0; r < 4; r++)
            stage[(i * 16 + q * 4 + r) * SROW_ + wn + j * 16 + l] = (bf16)acc[i][j][r];
    }
    __syncthreads();
#pragma unroll
    for (int pass = 0; pass < 4; pass++) {
      int u = pass * 256 + stid;
      int row = u >> 4, seg = u & 15;
      bf16x8 v = *(const bf16x8*)(stage + row * SROW_ + seg * 8);
      *(bf16x8*)(C + (long)(ph * 64 + row) * H_ + n0 + seg * 8) = v;
    }
    __syncthreads();
  }
}

// ---- rnn task body (1024 threads, 99840B LDS) — register-held U ----
__device__ void rnn_task(
    const bf16* __restrict__ xwc, const unsigned char* __restrict__ U8,
    const float* __restrict__ bias, int t0, int first, int blk,
    bf16* __restrict__ seq, char* smem, int tid) {
  char* hls8 = smem;                    // 2 x (32 x 520 B) fp8 h
  bf16* xws = (bf16*)(smem + 33280);    // 2 x (32 x 520) bf16: xw in / h out
  const int wave = tid >> 6, lane = tid & 63;
  const int l = lane & 15, q = lane >> 4;
  const int b0 = blk * ROWS_;

  // preload this wave's U slice into registers (hidden-tiles wave*2, wave*2+1)
  const unsigned char* Ub = U8 + (long)(wave * 2) * 8192 + lane * 16;
  u64x2 Ureg[8][2];
#pragma unroll
  for (int kk2 = 0; kk2 < 8; kk2++)
#pragma unroll
    for (int nt = 0; nt < 2; nt++)
      Ureg[kk2][nt] = *(const u64x2*)(Ub + nt * 8192 + kk2 * 1024);

  // init h_{t0-1} into hls8[0]: wave handles rows wave*2, wave*2+1
#pragma unroll
  for (int rr = 0; rr < 2; rr++) {
    int m = wave * 2 + rr;
    long pk = 0;
    if (!first) {
      const bf16* hsrc = seq + ((long)(t0 - 1) * B_ + b0 + m) * H_;
      bf16x8 v = *(const bf16x8*)(hsrc + lane * 8);
      float f[8];
#pragma unroll
      for (int j = 0; j < 8; j++) f[j] = (float)v[j] * 16.f;
      pk = pack_fp8x8(f);
    }
    *(long*)(hls8 + m * 520 + lane * 8) = pk;
  }

  float bb[2][4];
#pragma unroll
  for (int nt = 0; nt < 2; nt++)
#pragma unroll
    for (int r = 0; r < 4; r++)
      bb[nt][r] = bias[(wave * 2 + nt) * 16 + q * 4 + r];

  auto prefetch = [&](int tl2) {
    int buf = tl2 & 1;
#pragma unroll
    for (int rr = 0; rr < 2; rr++) {
      int row = wave * 2 + rr;
      __builtin_amdgcn_global_load_lds(
          (const AS1 void*)(xwc + ((long)tl2 * B_ + b0 + row) * H_ + lane * 8),
          (AS3 void*)(xws + (buf * ROWS_ + row) * 520), 16, 0, 0);
    }
  };

  prefetch(0);
  __syncthreads();  // xws buf 0 ready; hls8[0] visible

  for (int tl = 0; tl < TC_; tl++) {
    if (tl > 0) {
      const bf16* src = xws + (((tl - 1) & 1) * ROWS_) * 520;
      bf16* sp = seq + ((long)(t0 + tl - 1) * B_ + b0) * H_;
#pragma unroll
      for (int rr = 0; rr < 2; rr++) {
        int m = wave * 2 + rr;
        *(bf16x8*)(sp + (long)m * H_ + lane * 8) =
            *(const bf16x8*)(src + m * 520 + lane * 8);
      }
    }
    if (tl + 1 < TC_) prefetch(tl + 1);  // lands by this step's barrier

    const char* hb0 = hls8 + ((tl & 1) * ROWS_ + l) * 520 + q * 8;
    const char* hb1 = hb0 + 16 * 520;
    f32x4 acc[2][2] = {};
#pragma unroll
    for (int kk2 = 0; kk2 < 8; kk2++) {
      long h0a = *(const long*)(hb0 + kk2 * 64);
      long h0b = *(const long*)(hb0 + kk2 * 64 + 32);
      long h1a = *(const long*)(hb1 + kk2 * 64);
      long h1b = *(const long*)(hb1 + kk2 * 64 + 32);
#pragma unroll
      for (int nt = 0; nt < 2; nt++) {
        acc[nt][0] = __builtin_amdgcn_mfma_f32_16x16x32_fp8_fp8((long)Ureg[kk2][nt].x, h0a,
                                                                acc[nt][0], 0, 0, 0);
        acc[nt][1] = __builtin_amdgcn_mfma_f32_16x16x32_fp8_fp8((long)Ureg[kk2][nt].x, h1a,
                                                                acc[nt][1], 0, 0, 0);
        acc[nt][0] = __builtin_amdgcn_mfma_f32_16x16x32_fp8_fp8((long)Ureg[kk2][nt].y, h0b,
                                                                acc[nt][0], 0, 0, 0);
        acc[nt][1] = __builtin_amdgcn_mfma_f32_16x16x32_fp8_fp8((long)Ureg[kk2][nt].y, h1b,
                                                                acc[nt][1], 0, 0, 0);
      }
    }
#pragma unroll
    for (int nt = 0; nt < 2; nt++) {
      int hoff = (wave * 2 + nt) * 16 + q * 4;
#pragma unroll
      for (int bh = 0; bh < 2; bh++) {
        bf16* xp = xws + ((tl & 1) * ROWS_ + bh * 16 + l) * 520 + hoff;
        bf16x4 xv = *(const bf16x4*)xp;
        float hv[4];
#pragma unroll
        for (int r = 0; r < 4; r++)
          hv[r] = fast_tanh((float)xv[r] + bb[nt][r] + acc[nt][bh][r] * 0.0009765625f);
        unsigned pw = (unsigned)__builtin_amdgcn_cvt_pk_fp8_f32(
            hv[0] * 16.f, hv[1] * 16.f, 0, false);
        pw = (unsigned)__builtin_amdgcn_cvt_pk_fp8_f32(
            hv[2] * 16.f, hv[3] * 16.f, (int)pw, true);
        *(unsigned*)(hls8 + (((tl + 1) & 1) * ROWS_ + bh * 16 + l) * 520 + hoff) = pw;
        bf16x4 h4;
#pragma unroll
        for (int r = 0; r < 4; r++) h4[r] = (bf16)hv[r];
        *(bf16x4*)xp = h4;
      }
    }
    __syncthreads();  // one barrier/step
  }
  {
    const bf16* src = xws + (((TC_ - 1) & 1) * ROWS_) * 520;
    bf16* sp = seq + ((long)(t0 + TC_ - 1) * B_ + b0) * H_;
#pragma unroll
    for (int rr = 0; rr < 2; rr++) {
      int m = wave * 2 + rr;
      *(bf16x8*)(sp + (long)m * H_ + lane * 8) =
          *(const bf16x8*)(src + m * 520 + lane * 8);
    }
  }
}

struct GemmTasks {
  const bf16* A[4];
  const bf16* Bt[4];
  bf16* C[4];
  int kind[4];
  int t0[4];
};

struct RnnTasks {
  const bf16* xwc[4];
  const unsigned char* U8[4];
  const float* bias[4];
  int t0[4];
  int first[4];
};

// ---- Cooperative fused round. PLAIN __launch_bounds__(1024): the (1024,4)
// variant pinned VGPR=64 and spilled catastrophically (R18: 316MB WRITE). With
// the plain form the allocator uses the full 128/lane this 1-block/CU shape
// permits (proven by standalone rnn_multi).
__global__ __launch_bounds__(1024) void fused_round(
    GemmTasks gt, RnnTasks rt, int n, bf16* __restrict__ seq,
    const int* __restrict__ tokens, const float* __restrict__ emb) {
  __shared__ __align__(16) char smem[133120];
  const int tid = threadIdx.x;

  // phase 1: gemm tiles (all 256 blocks x 4 subgroups)
  {
    const int sub = tid >> 8, stid = tid & 255;
    char* base = smem + sub * 33280;
    for (int u = (int)blockIdx.x * 4 + sub; u < n * 512; u += 1024) {
      int task = u >> 9, tile = u & 511;
      int mt = tile & 127, ntl = tile >> 7;
      if (gt.kind[task] == 1)
        gemm_tile_embed(tokens, emb, gt.Bt[task], gt.C[task], gt.t0[task], mt, ntl, stid, base);
      else
        gemm_tile(gt.A[task], gt.Bt[task], gt.C[task], mt, ntl, stid, base);
    }
  }

  __threadfence();           // release: xw writes device-visible
  cg::this_grid().sync();
  __threadfence();           // acquire
  __syncthreads();           // smem handoff gemm -> rnn

  // phase 2: rnn
  if ((int)blockIdx.x < n * 64) {
    int task = blockIdx.x >> 6, blk = blockIdx.x & 63;
    rnn_task(rt.xwc[task], rt.U8[task], rt.bias[task], rt.t0[task], rt.first[task],
             blk, seq, smem, tid);
  }
}

// ---- Fallback (serial) wrappers ----
__global__ __launch_bounds__(256) void gemm_multi(
    GemmTasks gt, const int* __restrict__ tokens, const float* __restrict__ emb) {
  __shared__ __align__(16) char smem[33280];
  const int task = blockIdx.x >> 9;
  const int tile = blockIdx.x & 511;
  const int mt = tile & 127, ntl = tile >> 7;
  if (gt.kind[task] == 1)
    gemm_tile_embed(tokens, emb, gt.Bt[task], gt.C[task], gt.t0[task], mt, ntl,
                    threadIdx.x, smem);
  else
    gemm_tile(gt.A[task], gt.Bt[task], gt.C[task], mt, ntl, threadIdx.x, smem);
}

__global__ __launch_bounds__(1024) void rnn_multi(RnnTasks rt, bf16* __restrict__ seq) {
  __shared__ __align__(16) char smem[99840];
  int task = blockIdx.x >> 6, blk = blockIdx.x & 63;
  rnn_task(rt.xwc[task], rt.U8[task], rt.bias[task], rt.t0[task], rt.first[task],
           blk, seq, smem, threadIdx.x);
}

// out[b] = sigmoid(dot(seq[(T-1)*B + b, :], Wo) + bo)
__global__ __launch_bounds__(256) void head_kernel(
    const bf16* __restrict__ seq, const float* __restrict__ Wo,
    const float* __restrict__ bo, float* __restrict__ out) {
  int wave = threadIdx.x >> 6, lane = threadIdx.x & 63;
  int row = blockIdx.x * 4 + wave;
  const bf16* p = seq + ((long)(T_ - 1) * B_ + row) * H_ + lane * 8;
  bf16x8 v = *(const bf16x8*)p;
  float s = 0.f;
#pragma unroll
  for (int i = 0; i < 8; i++) s += (float)v[i] * Wo[lane * 8 + i];
#pragma unroll
  for (int off = 32; off; off >>= 1) s += __shfl_down(s, off, 64);
  if (lane == 0) {
    float x = s + bo[0];
    out[row] = 1.f / (1.f + exp2f(-x * 1.44269504088896f));
  }
}

extern "C" void kernel_launch(void* const* d_in, const int* in_sizes, int n_in,
                              void* d_out, int out_size, void* d_ws, size_t ws_size,
                              hipStream_t stream) {
  (void)in_sizes; (void)n_in; (void)out_size;
  const int*   tokens = (const int*)d_in[0];
  const float* emb = (const float*)d_in[1];
  const float* Ws[4] = {(const float*)d_in[2], (const float*)d_in[5],
                        (const float*)d_in[8], (const float*)d_in[11]};
  const float* Us[4] = {(const float*)d_in[3], (const float*)d_in[6],
                        (const float*)d_in[9], (const float*)d_in[12]};
  const float* bs[4] = {(const float*)d_in[4], (const float*)d_in[7],
                        (const float*)d_in[10], (const float*)d_in[13]};
  const float* Wo = (const float*)d_in[14];
  const float* bo = (const float*)d_in[15];
  float* out = (float*)d_out;

  char* w = (char*)d_ws;
  const size_t SEQ_BYTES = (size_t)T_ * B_ * H_ * 2;           // 160 MB
  const size_t WEIGHTS = (512 * 128 + 3 * 512 * 512) * 2 + 4 * 512 * 512;
  const size_t XWB = (size_t)TC_ * B_ * H_ * 2;                // 16 MB
  const bool wf = ws_size >= SEQ_BYTES + WEIGHTS + 4 * XWB;    // ~227.4 MB

  bf16* SEQ = (bf16*)w;
  char* wb = w + SEQ_BYTES;
  bf16* Wt[4];
  Wt[0] = (bf16*)wb;
  Wt[1] = Wt[0] + 512 * 128;
  Wt[2] = Wt[1] + 512 * 512;
  Wt[3] = Wt[2] + 512 * 512;
  unsigned char* Up[4];
  Up[0] = (unsigned char*)(Wt[3] + 512 * 512);
  Up[1] = Up[0] + 512 * 512;
  Up[2] = Up[1] + 512 * 512;
  Up[3] = Up[2] + 512 * 512;
  char* bankbase = w + SEQ_BYTES + WEIGHTS;
  bf16* BANK[4];
  for (int i = 0; i < 4; i++) BANK[i] = (bf16*)(bankbase + (size_t)i * XWB);

  {
    WConv wc{};
    UConv uc{};
    for (int i = 0; i < 4; i++) {
      wc.src[i] = Ws[i]; wc.dst[i] = Wt[i];
      wc.K[i] = (i == 0) ? 100 : 512;
      wc.Kp[i] = (i == 0) ? 128 : 512;
      uc.src[i] = Us[i]; uc.dst[i] = Up[i];
    }
    convert_weight_all<<<dim3(1024, 4), 256, 0, stream>>>(wc);
    convert_u_all<<<dim3(128, 4), 256, 0, stream>>>(uc);
  }

  if (wf) {
    // layer-wavefront, one cooperative launch per round
    for (int r = 0; r <= NC_ - 1 + L_ - 1; r++) {
      GemmTasks gt{};
      RnnTasks rt{};
      int n = 0;
      int lmin = r - (NC_ - 1); if (lmin < 0) lmin = 0;
      int lmax = r < L_ - 1 ? r : L_ - 1;
      for (int l = lmin; l <= lmax; l++) {
        int c = r - l;
        bf16* xb = BANK[l];
        gt.A[n] = SEQ + (size_t)c * TC_ * B_ * H_;
        gt.Bt[n] = Wt[l];
        gt.C[n] = xb;
        gt.kind[n] = (l == 0) ? 1 : 2;
        gt.t0[n] = c * TC_;
        rt.xwc[n] = xb;
        rt.U8[n] = Up[l];
        rt.bias[n] = bs[l];
        rt.t0[n] = c * TC_;
        rt.first[n] = (c == 0) ? 1 : 0;
        n++;
      }
      bf16* seqp = SEQ;
      void* kargs[] = {(void*)&gt, (void*)&rt, (void*)&n, (void*)&seqp,
                       (void*)&tokens, (void*)&emb};
      hipLaunchCooperativeKernel(reinterpret_cast<const void*>(&fused_round),
                                 dim3(256), dim3(1024), kargs, 0, stream);
    }
  } else {
    // serial fallback: 2 banks
    for (int l = 0; l < L_; l++) {
      for (int c = 0; c < NC_; c++) {
        bf16* xb = BANK[c & 1];
        GemmTasks gt{};
        RnnTasks rt{};
        gt.A[0] = SEQ + (size_t)c * TC_ * B_ * H_;
        gt.Bt[0] = Wt[l];
        gt.C[0] = xb;
        gt.kind[0] = (l == 0) ? 1 : 2;
        gt.t0[0] = c * TC_;
        rt.xwc[0] = xb;
        rt.U8[0] = Up[l];
        rt.bias[0] = bs[l];
        rt.t0[0] = c * TC_;
        rt.first[0] = (c == 0) ? 1 : 0;
        gemm_multi<<<512, 256, 0, stream>>>(gt, tokens, emb);
        rnn_multi<<<64, 1024, 0, stream>>>(rt, SEQ);
      }
    }
  }

  head_kernel<<<B_ / 4, 256, 0, stream>>>(SEQ, Wo, bo, out);
}

// Round 20
// 3975.917 us; speedup vs baseline: 1.1827x; 1.1775x over previous
//
#include <hip/hip_runtime.h>
#include <hip/hip_cooperative_groups.h>

namespace cg = cooperative_groups;

typedef __bf16 bf16;
typedef bf16 bf16x4 __attribute__((ext_vector_type(4)));
typedef bf16 bf16x8 __attribute__((ext_vector_type(8)));
typedef float f32x4 __attribute__((ext_vector_type(4)));
typedef unsigned long u64x2 __attribute__((ext_vector_type(2)));

#define AS1 __attribute__((address_space(1)))
#define AS3 __attribute__((address_space(3)))

#define B_ 2048
#define T_ 80
#define E_ 100
#define H_ 512
#define TC_ 8               // time-chunk
#define NC_ (T_ / TC_)      // 10 chunks
#define ROWS_ 32            // batch rows per rnn block (64 blocks/task)
#define L_ 4

// SEQ is TIME-MAJOR: seq[(t*B_ + b)*H_ + h]
// U fp8 A-OPERAND layout (operand-swapped rnn: D = (h@U)^T = mfma(A=U^T, B=h)):
//   hidden-tile ht, kk-pair p -> 1024B block at (ht*8+p)*1024;
//   byte[lane*16 + half*8 + j] = U[k=(2p+half)*32+(lane>>4)*8+j][ht*16+(lane&15)] * 2^6

__device__ __forceinline__ float fast_tanh(float x) {
  float e = exp2f(x * 2.8853900817779268f);  // e^{2x}
  return 1.f - 2.f * __builtin_amdgcn_rcpf(e + 1.f);
}

__device__ __forceinline__ long pack_fp8x8(const float* f) {
  int w0 = __builtin_amdgcn_cvt_pk_fp8_f32(f[0], f[1], 0, false);
  w0 = __builtin_amdgcn_cvt_pk_fp8_f32(f[2], f[3], w0, true);
  int w1 = __builtin_amdgcn_cvt_pk_fp8_f32(f[4], f[5], 0, false);
  w1 = __builtin_amdgcn_cvt_pk_fp8_f32(f[6], f[7], w1, true);
  return (long)(((unsigned long)(unsigned)w1 << 32) | (unsigned)w0);
}

// ---- Merged weight conversion (2 launches) ----

struct WConv {
  const float* src[4];
  bf16* dst[4];
  int K[4];
  int Kp[4];
};

__global__ void convert_weight_all(WConv wc) {
  int layer = blockIdx.y;
  int idx = blockIdx.x * 256 + threadIdx.x;
  int K = wc.K[layer], Kp = wc.Kp[layer];
  if (idx >= 512 * Kp) return;
  int n = idx / Kp, k = idx - n * Kp;
  float v = (k < K) ? wc.src[layer][(long)k * 512 + n] : 0.f;
  wc.dst[layer][idx] = (bf16)v;
}

struct UConv {
  const float* src[4];
  unsigned char* dst[4];
};

__global__ void convert_u_all(UConv uc) {
  int layer = blockIdx.y;
  int idx = blockIdx.x * 256 + threadIdx.x;
  int half = idx & 1, lane = (idx >> 1) & 63, p = (idx >> 7) & 7, ht = idx >> 10;
  int q = lane >> 4;
  int k0 = (2 * p + half) * 32 + q * 8;
  int n = ht * 16 + (lane & 15);
  float f[8];
#pragma unroll
  for (int j = 0; j < 8; j++) f[j] = uc.src[layer][(long)(k0 + j) * H_ + n] * 64.f;
  *(long*)(uc.dst[layer] + (long)(ht * 8 + p) * 1024 + lane * 16 + half * 8) = pack_fp8x8(f);
}

// ---- GEMM tile device functions (256-thread sub-group, 33280B LDS slice) ----
// FORCEINLINE IS LOAD-BEARING: without it these compile as ABI calls ->
// VGPR pinned at 64 + scratch spill (R18/R19: 316MB WRITE, 372us rounds).

#define SROW_ 136  // stage row stride in bf16 (272 B)

__device__ __forceinline__ void gemm_tile(
    const bf16* __restrict__ A, const bf16* __restrict__ Bt, bf16* __restrict__ C,
    int mtile, int ntile, int stid, char* base) {
  bf16* As0 = (bf16*)base;
  bf16* Bs0 = (bf16*)(base + 8192);
  bf16* As1 = (bf16*)(base + 16384);
  bf16* Bs1 = (bf16*)(base + 24576);
  const int K = 512;
  const int wave = stid >> 6, lane = stid & 63;
  const int l = lane & 15, q = lane >> 4;
  const long m0 = (long)mtile * 128;
  const int n0 = ntile * 128;
  const int wm = (wave >> 1) * 64, wn = (wave & 1) * 64;

  f32x4 acc[4][4] = {};

  const int e0 = stid, e1 = 256 + stid;
  const int r0 = e0 >> 2, c0 = e0 & 3;
  const int r1 = e1 >> 2, c1 = e1 & 3;
  const int s0 = c0 ^ (r0 & 3) ^ ((r0 >> 2) & 3);
  const int s1 = c1 ^ (r1 & 3) ^ ((r1 >> 2) & 3);
  const int swr = q ^ (l & 3) ^ ((l >> 2) & 3);

  const bf16* A0 = A + (m0 + r0) * K + s0 * 8;
  const bf16* A1 = A + (m0 + r1) * K + s1 * 8;
  const bf16* B0 = Bt + (long)(n0 + r0) * K + s0 * 8;
  const bf16* B1 = Bt + (long)(n0 + r1) * K + s1 * 8;
  const int w0o = (wave * 64) * 8, w1o = (256 + wave * 64) * 8;

  for (int k0 = 0; k0 < K; k0 += 64) {
    __builtin_amdgcn_global_load_lds((const AS1 void*)(A0 + k0), (AS3 void*)(As0 + w0o), 16, 0, 0);
    __builtin_amdgcn_global_load_lds((const AS1 void*)(A1 + k0), (AS3 void*)(As0 + w1o), 16, 0, 0);
    __builtin_amdgcn_global_load_lds((const AS1 void*)(B0 + k0), (AS3 void*)(Bs0 + w0o), 16, 0, 0);
    __builtin_amdgcn_global_load_lds((const AS1 void*)(B1 + k0), (AS3 void*)(Bs0 + w1o), 16, 0, 0);
    __builtin_amdgcn_global_load_lds((const AS1 void*)(A0 + k0 + 32), (AS3 void*)(As1 + w0o), 16, 0, 0);
    __builtin_amdgcn_global_load_lds((const AS1 void*)(A1 + k0 + 32), (AS3 void*)(As1 + w1o), 16, 0, 0);
    __builtin_amdgcn_global_load_lds((const AS1 void*)(B0 + k0 + 32), (AS3 void*)(Bs1 + w0o), 16, 0, 0);
    __builtin_amdgcn_global_load_lds((const AS1 void*)(B1 + k0 + 32), (AS3 void*)(Bs1 + w1o), 16, 0, 0);
    __syncthreads();
    bf16x8 af0[4], bf0[4], af1[4], bf1[4];
#pragma unroll
    for (int i = 0; i < 4; i++) {
      af0[i] = *(const bf16x8*)(As0 + (wm + i * 16 + l) * 32 + swr * 8);
      bf0[i] = *(const bf16x8*)(Bs0 + (wn + i * 16 + l) * 32 + swr * 8);
      af1[i] = *(const bf16x8*)(As1 + (wm + i * 16 + l) * 32 + swr * 8);
      bf1[i] = *(const bf16x8*)(Bs1 + (wn + i * 16 + l) * 32 + swr * 8);
    }
#pragma unroll
    for (int i = 0; i < 4; i++)
#pragma unroll
      for (int j = 0; j < 4; j++) {
        acc[i][j] = __builtin_amdgcn_mfma_f32_16x16x32_bf16(af0[i], bf0[j], acc[i][j], 0, 0, 0);
        acc[i][j] = __builtin_amdgcn_mfma_f32_16x16x32_bf16(af1[i], bf1[j], acc[i][j], 0, 0, 0);
      }
    __syncthreads();
  }
  // LDS-staged coalesced store
  bf16* stage = (bf16*)base;
#pragma unroll
  for (int ph = 0; ph < 2; ph++) {
    if (wm == ph * 64) {
#pragma unroll
      for (int i = 0; i < 4; i++)
#pragma unroll
        for (int j = 0; j < 4; j++)
#pragma unroll
          for (int r = 0; r < 4; r++)
            stage[(i * 16 + q * 4 + r) * SROW_ + wn + j * 16 + l] = (bf16)acc[i][j][r];
    }
    __syncthreads();
#pragma unroll
    for (int pass = 0; pass < 4; pass++) {
      int u = pass * 256 + stid;
      int row = u >> 4, seg = u & 15;
      bf16x8 v = *(const bf16x8*)(stage + row * SROW_ + seg * 8);
      *(bf16x8*)(C + (m0 + ph * 64 + row) * (long)H_ + n0 + seg * 8) = v;
    }
    __syncthreads();
  }
}

// layer-1 tile with fused embedding gather; mtile -> (trow, b0); K=128 (padded E)
__device__ __forceinline__ void gemm_tile_embed(
    const int* __restrict__ tokens, const float* __restrict__ emb,
    const bf16* __restrict__ Bt, bf16* __restrict__ xwc, int t0,
    int mtile, int ntile, int stid, char* base) {
  bf16* As0 = (bf16*)base;
  bf16* Bs0 = (bf16*)(base + 8192);
  bf16* As1 = (bf16*)(base + 16384);
  bf16* Bs1 = (bf16*)(base + 24576);
  int* stok = (int*)(base + 32768);
  const int K = 128;
  const int wave = stid >> 6, lane = stid & 63;
  const int l = lane & 15, q = lane >> 4;
  const int trow = mtile >> 4;
  const int b0 = (mtile & 15) * 128;
  const int t = t0 + trow;
  const int n0 = ntile * 128;
  const int wm = (wave >> 1) * 64, wn = (wave & 1) * 64;

  if (stid < 128) stok[stid] = tokens[(b0 + stid) * T_ + t];
  __syncthreads();

  f32x4 acc[4][4] = {};

  const int e0 = stid, e1 = 256 + stid;
  const int r0 = e0 >> 2, c0 = e0 & 3;
  const int r1 = e1 >> 2, c1 = e1 & 3;
  const int s0 = c0 ^ (r0 & 3) ^ ((r0 >> 2) & 3);
  const int s1 = c1 ^ (r1 & 3) ^ ((r1 >> 2) & 3);
  const int swr = q ^ (l & 3) ^ ((l >> 2) & 3);

  const bf16* B0 = Bt + (long)(n0 + r0) * K + s0 * 8;
  const bf16* B1 = Bt + (long)(n0 + r1) * K + s1 * 8;
  const int w0o = (wave * 64) * 8, w1o = (256 + wave * 64) * 8;

  const int ar = stid >> 1, hh = stid & 1;
  const int asw = (ar & 3) ^ ((ar >> 2) & 3);
  const float* er = emb + (long)stok[ar] * E_;

  for (int k0 = 0; k0 < K; k0 += 64) {
    __builtin_amdgcn_global_load_lds((const AS1 void*)(B0 + k0), (AS3 void*)(Bs0 + w0o), 16, 0, 0);
    __builtin_amdgcn_global_load_lds((const AS1 void*)(B1 + k0), (AS3 void*)(Bs0 + w1o), 16, 0, 0);
    __builtin_amdgcn_global_load_lds((const AS1 void*)(B0 + k0 + 32), (AS3 void*)(Bs1 + w0o), 16, 0, 0);
    __builtin_amdgcn_global_load_lds((const AS1 void*)(B1 + k0 + 32), (AS3 void*)(Bs1 + w1o), 16, 0, 0);
#pragma unroll
    for (int set = 0; set < 2; set++) {
      bf16* Asx = set ? As1 : As0;
      int kb0 = k0 + set * 32;
      bf16x8 v[2];
#pragma unroll
      for (int cch = 0; cch < 2; cch++) {
        int kb = kb0 + hh * 16 + cch * 8;
#pragma unroll
        for (int j = 0; j < 8; j++) {
          int k = kb + j;
          v[cch][j] = (bf16)((k < E_) ? er[k] : 0.f);
        }
      }
      *(bf16x8*)(Asx + ar * 32 + ((2 * hh + 0) ^ asw) * 8) = v[0];
      *(bf16x8*)(Asx + ar * 32 + ((2 * hh + 1) ^ asw) * 8) = v[1];
    }
    __syncthreads();
    bf16x8 af0[4], bf0[4], af1[4], bf1[4];
#pragma unroll
    for (int i = 0; i < 4; i++) {
      af0[i] = *(const bf16x8*)(As0 + (wm + i * 16 + l) * 32 + swr * 8);
      bf0[i] = *(const bf16x8*)(Bs0 + (wn + i * 16 + l) * 32 + swr * 8);
      af1[i] = *(const bf16x8*)(As1 + (wm + i * 16 + l) * 32 + swr * 8);
      bf1[i] = *(const bf16x8*)(Bs1 + (wn + i * 16 + l) * 32 + swr * 8);
    }
#pragma unroll
    for (int i = 0; i < 4; i++)
#pragma unroll
      for (int j = 0; j < 4; j++) {
        acc[i][j] = __builtin_amdgcn_mfma_f32_16x16x32_bf16(af0[i], bf0[j], acc[i][j], 0, 0, 0);
        acc[i][j] = __builtin_amdgcn_mfma_f32_16x16x32_bf16(af1[i], bf1[j], acc[i][j], 0, 0, 0);
      }
    __syncthreads();
  }
  // LDS-staged coalesced store
  bf16* C = xwc + ((long)trow * B_ + b0) * H_;
  bf16* stage = (bf16*)base;
#pragma unroll
  for (int ph = 0; ph < 2; ph++) {
    if (wm == ph * 64) {
#pragma unroll
      for (int i = 0; i < 4; i++)
#pragma unroll
        for (int j = 0; j < 4; j++)
#pragma unroll
          for (int r = 0; r < 4; r++)
            stage[(i * 16 + q * 4 + r) * SROW_ + wn + j * 16 + l] = (bf16)acc[i][j][r];
    }
    __syncthreads();
#pragma unroll
    for (int pass = 0; pass < 4; pass++) {
      int u = pass * 256 + stid;
      int row = u >> 4, seg = u & 15;
      bf16x8 v = *(const bf16x8*)(stage + row * SROW_ + seg * 8);
      *(bf16x8*)(C + (long)(ph * 64 + row) * H_ + n0 + seg * 8) = v;
    }
    __syncthreads();
  }
}

// ---- rnn task body (1024 threads, 99840B LDS) — register-held U ----
__device__ __forceinline__ void rnn_task(
    const bf16* __restrict__ xwc, const unsigned char* __restrict__ U8,
    const float* __restrict__ bias, int t0, int first, int blk,
    bf16* __restrict__ seq, char* smem, int tid) {
  char* hls8 = smem;                    // 2 x (32 x 520 B) fp8 h
  bf16* xws = (bf16*)(smem + 33280);    // 2 x (32 x 520) bf16: xw in / h out
  const int wave = tid >> 6, lane = tid & 63;
  const int l = lane & 15, q = lane >> 4;
  const int b0 = blk * ROWS_;

  // preload this wave's U slice into registers (hidden-tiles wave*2, wave*2+1)
  const unsigned char* Ub = U8 + (long)(wave * 2) * 8192 + lane * 16;
  u64x2 Ureg[8][2];
#pragma unroll
  for (int kk2 = 0; kk2 < 8; kk2++)
#pragma unroll
    for (int nt = 0; nt < 2; nt++)
      Ureg[kk2][nt] = *(const u64x2*)(Ub + nt * 8192 + kk2 * 1024);

  // init h_{t0-1} into hls8[0]: wave handles rows wave*2, wave*2+1
#pragma unroll
  for (int rr = 0; rr < 2; rr++) {
    int m = wave * 2 + rr;
    long pk = 0;
    if (!first) {
      const bf16* hsrc = seq + ((long)(t0 - 1) * B_ + b0 + m) * H_;
      bf16x8 v = *(const bf16x8*)(hsrc + lane * 8);
      float f[8];
#pragma unroll
      for (int j = 0; j < 8; j++) f[j] = (float)v[j] * 16.f;
      pk = pack_fp8x8(f);
    }
    *(long*)(hls8 + m * 520 + lane * 8) = pk;
  }

  float bb[2][4];
#pragma unroll
  for (int nt = 0; nt < 2; nt++)
#pragma unroll
    for (int r = 0; r < 4; r++)
      bb[nt][r] = bias[(wave * 2 + nt) * 16 + q * 4 + r];

  auto prefetch = [&](int tl2) {
    int buf = tl2 & 1;
#pragma unroll
    for (int rr = 0; rr < 2; rr++) {
      int row = wave * 2 + rr;
      __builtin_amdgcn_global_load_lds(
          (const AS1 void*)(xwc + ((long)tl2 * B_ + b0 + row) * H_ + lane * 8),
          (AS3 void*)(xws + (buf * ROWS_ + row) * 520), 16, 0, 0);
    }
  };

  prefetch(0);
  __syncthreads();  // xws buf 0 ready; hls8[0] visible

  for (int tl = 0; tl < TC_; tl++) {
    if (tl > 0) {
      const bf16* src = xws + (((tl - 1) & 1) * ROWS_) * 520;
      bf16* sp = seq + ((long)(t0 + tl - 1) * B_ + b0) * H_;
#pragma unroll
      for (int rr = 0; rr < 2; rr++) {
        int m = wave * 2 + rr;
        *(bf16x8*)(sp + (long)m * H_ + lane * 8) =
            *(const bf16x8*)(src + m * 520 + lane * 8);
      }
    }
    if (tl + 1 < TC_) prefetch(tl + 1);  // lands by this step's barrier

    const char* hb0 = hls8 + ((tl & 1) * ROWS_ + l) * 520 + q * 8;
    const char* hb1 = hb0 + 16 * 520;
    f32x4 acc[2][2] = {};
#pragma unroll
    for (int kk2 = 0; kk2 < 8; kk2++) {
      long h0a = *(const long*)(hb0 + kk2 * 64);
      long h0b = *(const long*)(hb0 + kk2 * 64 + 32);
      long h1a = *(const long*)(hb1 + kk2 * 64);
      long h1b = *(const long*)(hb1 + kk2 * 64 + 32);
#pragma unroll
      for (int nt = 0; nt < 2; nt++) {
        acc[nt][0] = __builtin_amdgcn_mfma_f32_16x16x32_fp8_fp8((long)Ureg[kk2][nt].x, h0a,
                                                                acc[nt][0], 0, 0, 0);
        acc[nt][1] = __builtin_amdgcn_mfma_f32_16x16x32_fp8_fp8((long)Ureg[kk2][nt].x, h1a,
                                                                acc[nt][1], 0, 0, 0);
        acc[nt][0] = __builtin_amdgcn_mfma_f32_16x16x32_fp8_fp8((long)Ureg[kk2][nt].y, h0b,
                                                                acc[nt][0], 0, 0, 0);
        acc[nt][1] = __builtin_amdgcn_mfma_f32_16x16x32_fp8_fp8((long)Ureg[kk2][nt].y, h1b,
                                                                acc[nt][1], 0, 0, 0);
      }
    }
#pragma unroll
    for (int nt = 0; nt < 2; nt++) {
      int hoff = (wave * 2 + nt) * 16 + q * 4;
#pragma unroll
      for (int bh = 0; bh < 2; bh++) {
        bf16* xp = xws + ((tl & 1) * ROWS_ + bh * 16 + l) * 520 + hoff;
        bf16x4 xv = *(const bf16x4*)xp;
        float hv[4];
#pragma unroll
        for (int r = 0; r < 4; r++)
          hv[r] = fast_tanh((float)xv[r] + bb[nt][r] + acc[nt][bh][r] * 0.0009765625f);
        unsigned pw = (unsigned)__builtin_amdgcn_cvt_pk_fp8_f32(
            hv[0] * 16.f, hv[1] * 16.f, 0, false);
        pw = (unsigned)__builtin_amdgcn_cvt_pk_fp8_f32(
            hv[2] * 16.f, hv[3] * 16.f, (int)pw, true);
        *(unsigned*)(hls8 + (((tl + 1) & 1) * ROWS_ + bh * 16 + l) * 520 + hoff) = pw;
        bf16x4 h4;
#pragma unroll
        for (int r = 0; r < 4; r++) h4[r] = (bf16)hv[r];
        *(bf16x4*)xp = h4;
      }
    }
    __syncthreads();  // one barrier/step
  }
  {
    const bf16* src = xws + (((TC_ - 1) & 1) * ROWS_) * 520;
    bf16* sp = seq + ((long)(t0 + TC_ - 1) * B_ + b0) * H_;
#pragma unroll
    for (int rr = 0; rr < 2; rr++) {
      int m = wave * 2 + rr;
      *(bf16x8*)(sp + (long)m * H_ + lane * 8) =
          *(const bf16x8*)(src + m * 520 + lane * 8);
    }
  }
}

struct GemmTasks {
  const bf16* A[4];
  const bf16* Bt[4];
  bf16* C[4];
  int kind[4];
  int t0[4];
};

struct RnnTasks {
  const bf16* xwc[4];
  const unsigned char* U8[4];
  const float* bias[4];
  int t0[4];
  int first[4];
};

// ---- Cooperative fused round ----
__global__ __launch_bounds__(1024) void fused_round(
    GemmTasks gt, RnnTasks rt, int n, bf16* __restrict__ seq,
    const int* __restrict__ tokens, const float* __restrict__ emb) {
  __shared__ __align__(16) char smem[133120];
  const int tid = threadIdx.x;

  // phase 1: gemm tiles (all 256 blocks x 4 subgroups)
  {
    const int sub = tid >> 8, stid = tid & 255;
    char* base = smem + sub * 33280;
    for (int u = (int)blockIdx.x * 4 + sub; u < n * 512; u += 1024) {
      int task = u >> 9, tile = u & 511;
      int mt = tile & 127, ntl = tile >> 7;
      if (gt.kind[task] == 1)
        gemm_tile_embed(tokens, emb, gt.Bt[task], gt.C[task], gt.t0[task], mt, ntl, stid, base);
      else
        gemm_tile(gt.A[task], gt.Bt[task], gt.C[task], mt, ntl, stid, base);
    }
  }

  __threadfence();           // release: xw writes device-visible
  cg::this_grid().sync();
  __threadfence();           // acquire
  __syncthreads();           // smem handoff gemm -> rnn

  // phase 2: rnn
  if ((int)blockIdx.x < n * 64) {
    int task = blockIdx.x >> 6, blk = blockIdx.x & 63;
    rnn_task(rt.xwc[task], rt.U8[task], rt.bias[task], rt.t0[task], rt.first[task],
             blk, seq, smem, tid);
  }
}

// ---- Fallback (serial) wrappers ----
__global__ __launch_bounds__(256) void gemm_multi(
    GemmTasks gt, const int* __restrict__ tokens, const float* __restrict__ emb) {
  __shared__ __align__(16) char smem[33280];
  const int task = blockIdx.x >> 9;
  const int tile = blockIdx.x & 511;
  const int mt = tile & 127, ntl = tile >> 7;
  if (gt.kind[task] == 1)
    gemm_tile_embed(tokens, emb, gt.Bt[task], gt.C[task], gt.t0[task], mt, ntl,
                    threadIdx.x, smem);
  else
    gemm_tile(gt.A[task], gt.Bt[task], gt.C[task], mt, ntl, threadIdx.x, smem);
}

__global__ __launch_bounds__(1024) void rnn_multi(RnnTasks rt, bf16* __restrict__ seq) {
  __shared__ __align__(16) char smem[99840];
  int task = blockIdx.x >> 6, blk = blockIdx.x & 63;
  rnn_task(rt.xwc[task], rt.U8[task], rt.bias[task], rt.t0[task], rt.first[task],
           blk, seq, smem, threadIdx.x);
}

// out[b] = sigmoid(dot(seq[(T-1)*B + b, :], Wo) + bo)
__global__ __launch_bounds__(256) void head_kernel(
    const bf16* __restrict__ seq, const float* __restrict__ Wo,
    const float* __restrict__ bo, float* __restrict__ out) {
  int wave = threadIdx.x >> 6, lane = threadIdx.x & 63;
  int row = blockIdx.x * 4 + wave;
  const bf16* p = seq + ((long)(T_ - 1) * B_ + row) * H_ + lane * 8;
  bf16x8 v = *(const bf16x8*)p;
  float s = 0.f;
#pragma unroll
  for (int i = 0; i < 8; i++) s += (float)v[i] * Wo[lane * 8 + i];
#pragma unroll
  for (int off = 32; off; off >>= 1) s += __shfl_down(s, off, 64);
  if (lane == 0) {
    float x = s + bo[0];
    out[row] = 1.f / (1.f + exp2f(-x * 1.44269504088896f));
  }
}

extern "C" void kernel_launch(void* const* d_in, const int* in_sizes, int n_in,
                              void* d_out, int out_size, void* d_ws, size_t ws_size,
                              hipStream_t stream) {
  (void)in_sizes; (void)n_in; (void)out_size;
  const int*   tokens = (const int*)d_in[0];
  const float* emb = (const float*)d_in[1];
  const float* Ws[4] = {(const float*)d_in[2], (const float*)d_in[5],
                        (const float*)d_in[8], (const float*)d_in[11]};
  const float* Us[4] = {(const float*)d_in[3], (const float*)d_in[6],
                        (const float*)d_in[9], (const float*)d_in[12]};
  const float* bs[4] = {(const float*)d_in[4], (const float*)d_in[7],
                        (const float*)d_in[10], (const float*)d_in[13]};
  const float* Wo = (const float*)d_in[14];
  const float* bo = (const float*)d_in[15];
  float* out = (float*)d_out;

  char* w = (char*)d_ws;
  const size_t SEQ_BYTES = (size_t)T_ * B_ * H_ * 2;           // 160 MB
  const size_t WEIGHTS = (512 * 128 + 3 * 512 * 512) * 2 + 4 * 512 * 512;
  const size_t XWB = (size_t)TC_ * B_ * H_ * 2;                // 16 MB
  const bool wf = ws_size >= SEQ_BYTES + WEIGHTS + 4 * XWB;    // ~227.4 MB

  bf16* SEQ = (bf16*)w;
  char* wb = w + SEQ_BYTES;
  bf16* Wt[4];
  Wt[0] = (bf16*)wb;
  Wt[1] = Wt[0] + 512 * 128;
  Wt[2] = Wt[1] + 512 * 512;
  Wt[3] = Wt[2] + 512 * 512;
  unsigned char* Up[4];
  Up[0] = (unsigned char*)(Wt[3] + 512 * 512);
  Up[1] = Up[0] + 512 * 512;
  Up[2] = Up[1] + 512 * 512;
  Up[3] = Up[2] + 512 * 512;
  char* bankbase = w + SEQ_BYTES + WEIGHTS;
  bf16* BANK[4];
  for (int i = 0; i < 4; i++) BANK[i] = (bf16*)(bankbase + (size_t)i * XWB);

  {
    WConv wc{};
    UConv uc{};
    for (int i = 0; i < 4; i++) {
      wc.src[i] = Ws[i]; wc.dst[i] = Wt[i];
      wc.K[i] = (i == 0) ? 100 : 512;
      wc.Kp[i] = (i == 0) ? 128 : 512;
      uc.src[i] = Us[i]; uc.dst[i] = Up[i];
    }
    convert_weight_all<<<dim3(1024, 4), 256, 0, stream>>>(wc);
    convert_u_all<<<dim3(128, 4), 256, 0, stream>>>(uc);
  }

  if (wf) {
    // layer-wavefront, one cooperative launch per round
    for (int r = 0; r <= NC_ - 1 + L_ - 1; r++) {
      GemmTasks gt{};
      RnnTasks rt{};
      int n = 0;
      int lmin = r - (NC_ - 1); if (lmin < 0) lmin = 0;
      int lmax = r < L_ - 1 ? r : L_ - 1;
      for (int l = lmin; l <= lmax; l++) {
        int c = r - l;
        bf16* xb = BANK[l];
        gt.A[n] = SEQ + (size_t)c * TC_ * B_ * H_;
        gt.Bt[n] = Wt[l];
        gt.C[n] = xb;
        gt.kind[n] = (l == 0) ? 1 : 2;
        gt.t0[n] = c * TC_;
        rt.xwc[n] = xb;
        rt.U8[n] = Up[l];
        rt.bias[n] = bs[l];
        rt.t0[n] = c * TC_;
        rt.first[n] = (c == 0) ? 1 : 0;
        n++;
      }
      bf16* seqp = SEQ;
      void* kargs[] = {(void*)&gt, (void*)&rt, (void*)&n, (void*)&seqp,
                       (void*)&tokens, (void*)&emb};
      hipLaunchCooperativeKernel(reinterpret_cast<const void*>(&fused_round),
                                 dim3(256), dim3(1024), kargs, 0, stream);
    }
  } else {
    // serial fallback: 2 banks
    for (int l = 0; l < L_; l++) {
      for (int c = 0; c < NC_; c++) {
        bf16* xb = BANK[c & 1];
        GemmTasks gt{};
        RnnTasks rt{};
        gt.A[0] = SEQ + (size_t)c * TC_ * B_ * H_;
        gt.Bt[0] = Wt[l];
        gt.C[0] = xb;
        gt.kind[0] = (l == 0) ? 1 : 2;
        gt.t0[0] = c * TC_;
        rt.xwc[0] = xb;
        rt.U8[0] = Up[l];
        rt.bias[0] = bs[l];
        rt.t0[0] = c * TC_;
        rt.first[0] = (c == 0) ? 1 : 0;
        gemm_multi<<<512, 256, 0, stream>>>(gt, tokens, emb);
        rnn_multi<<<64, 1024, 0, stream>>>(rt, SEQ);
      }
    }
  }

  head_kernel<<<B_ / 4, 256, 0, stream>>>(SEQ, Wo, bo, out);
}

// Round 21
// 1046.033 us; speedup vs baseline: 4.4953x; 3.8009x over previous
//
#include <hip/hip_runtime.h>

typedef __bf16 bf16;
typedef bf16 bf16x4 __attribute__((ext_vector_type(4)));
typedef bf16 bf16x8 __attribute__((ext_vector_type(8)));
typedef float f32x4 __attribute__((ext_vector_type(4)));
typedef unsigned long u64x2 __attribute__((ext_vector_type(2)));

#define AS1 __attribute__((address_space(1)))
#define AS3 __attribute__((address_space(3)))

#define B_ 2048
#define T_ 80
#define E_ 100
#define H_ 512
#define TC_ 8               // time-chunk
#define NC_ (T_ / TC_)      // 10 chunks
#define ROWS_ 32            // batch rows per rnn block (64 blocks/task)
#define L_ 4

// SEQ is TIME-MAJOR: seq[(t*B_ + b)*H_ + h]
// U fp8 A-OPERAND layout (operand-swapped rnn: D = (h@U)^T = mfma(A=U^T, B=h)):
//   hidden-tile ht, kk-pair p -> 1024B block at (ht*8+p)*1024;
//   byte[lane*16 + half*8 + j] = U[k=(2p+half)*32+(lane>>4)*8+j][ht*16+(lane&15)] * 2^6

__device__ __forceinline__ float fast_tanh(float x) {
  float e = exp2f(x * 2.8853900817779268f);  // e^{2x}
  return 1.f - 2.f * __builtin_amdgcn_rcpf(e + 1.f);
}

__device__ __forceinline__ long pack_fp8x8(const float* f) {
  int w0 = __builtin_amdgcn_cvt_pk_fp8_f32(f[0], f[1], 0, false);
  w0 = __builtin_amdgcn_cvt_pk_fp8_f32(f[2], f[3], w0, true);
  int w1 = __builtin_amdgcn_cvt_pk_fp8_f32(f[4], f[5], 0, false);
  w1 = __builtin_amdgcn_cvt_pk_fp8_f32(f[6], f[7], w1, true);
  return (long)(((unsigned long)(unsigned)w1 << 32) | (unsigned)w0);
}

// ---- Merged weight conversion (2 launches) ----

struct WConv {
  const float* src[4];
  bf16* dst[4];
  int K[4];
  int Kp[4];
};

__global__ void convert_weight_all(WConv wc) {
  int layer = blockIdx.y;
  int idx = blockIdx.x * 256 + threadIdx.x;
  int K = wc.K[layer], Kp = wc.Kp[layer];
  if (idx >= 512 * Kp) return;
  int n = idx / Kp, k = idx - n * Kp;
  float v = (k < K) ? wc.src[layer][(long)k * 512 + n] : 0.f;
  wc.dst[layer][idx] = (bf16)v;
}

struct UConv {
  const float* src[4];
  unsigned char* dst[4];
};

__global__ void convert_u_all(UConv uc) {
  int layer = blockIdx.y;
  int idx = blockIdx.x * 256 + threadIdx.x;
  int half = idx & 1, lane = (idx >> 1) & 63, p = (idx >> 7) & 7, ht = idx >> 10;
  int q = lane >> 4;
  int k0 = (2 * p + half) * 32 + q * 8;
  int n = ht * 16 + (lane & 15);
  float f[8];
#pragma unroll
  for (int j = 0; j < 8; j++) f[j] = uc.src[layer][(long)(k0 + j) * H_ + n] * 64.f;
  *(long*)(uc.dst[layer] + (long)(ht * 8 + p) * 1024 + lane * 16 + half * 8) = pack_fp8x8(f);
}

// ---- GEMM tile device functions (256-thread block, 33280B LDS) ----
// R16-proven single-buffer BK=64 (measured best 46.5us/4-task round).

#define SROW_ 136  // stage row stride in bf16 (272 B)

__device__ __forceinline__ void gemm_tile(
    const bf16* __restrict__ A, const bf16* __restrict__ Bt, bf16* __restrict__ C,
    int mtile, int ntile, int stid, char* base) {
  bf16* As0 = (bf16*)base;
  bf16* Bs0 = (bf16*)(base + 8192);
  bf16* As1 = (bf16*)(base + 16384);
  bf16* Bs1 = (bf16*)(base + 24576);
  const int K = 512;
  const int wave = stid >> 6, lane = stid & 63;
  const int l = lane & 15, q = lane >> 4;
  const long m0 = (long)mtile * 128;
  const int n0 = ntile * 128;
  const int wm = (wave >> 1) * 64, wn = (wave & 1) * 64;

  f32x4 acc[4][4] = {};

  const int e0 = stid, e1 = 256 + stid;
  const int r0 = e0 >> 2, c0 = e0 & 3;
  const int r1 = e1 >> 2, c1 = e1 & 3;
  const int s0 = c0 ^ (r0 & 3) ^ ((r0 >> 2) & 3);
  const int s1 = c1 ^ (r1 & 3) ^ ((r1 >> 2) & 3);
  const int swr = q ^ (l & 3) ^ ((l >> 2) & 3);

  const bf16* A0 = A + (m0 + r0) * K + s0 * 8;
  const bf16* A1 = A + (m0 + r1) * K + s1 * 8;
  const bf16* B0 = Bt + (long)(n0 + r0) * K + s0 * 8;
  const bf16* B1 = Bt + (long)(n0 + r1) * K + s1 * 8;
  const int w0o = (wave * 64) * 8, w1o = (256 + wave * 64) * 8;

  for (int k0 = 0; k0 < K; k0 += 64) {
    __builtin_amdgcn_global_load_lds((const AS1 void*)(A0 + k0), (AS3 void*)(As0 + w0o), 16, 0, 0);
    __builtin_amdgcn_global_load_lds((const AS1 void*)(A1 + k0), (AS3 void*)(As0 + w1o), 16, 0, 0);
    __builtin_amdgcn_global_load_lds((const AS1 void*)(B0 + k0), (AS3 void*)(Bs0 + w0o), 16, 0, 0);
    __builtin_amdgcn_global_load_lds((const AS1 void*)(B1 + k0), (AS3 void*)(Bs0 + w1o), 16, 0, 0);
    __builtin_amdgcn_global_load_lds((const AS1 void*)(A0 + k0 + 32), (AS3 void*)(As1 + w0o), 16, 0, 0);
    __builtin_amdgcn_global_load_lds((const AS1 void*)(A1 + k0 + 32), (AS3 void*)(As1 + w1o), 16, 0, 0);
    __builtin_amdgcn_global_load_lds((const AS1 void*)(B0 + k0 + 32), (AS3 void*)(Bs1 + w0o), 16, 0, 0);
    __builtin_amdgcn_global_load_lds((const AS1 void*)(B1 + k0 + 32), (AS3 void*)(Bs1 + w1o), 16, 0, 0);
    __syncthreads();
    bf16x8 af0[4], bf0[4], af1[4], bf1[4];
#pragma unroll
    for (int i = 0; i < 4; i++) {
      af0[i] = *(const bf16x8*)(As0 + (wm + i * 16 + l) * 32 + swr * 8);
      bf0[i] = *(const bf16x8*)(Bs0 + (wn + i * 16 + l) * 32 + swr * 8);
      af1[i] = *(const bf16x8*)(As1 + (wm + i * 16 + l) * 32 + swr * 8);
      bf1[i] = *(const bf16x8*)(Bs1 + (wn + i * 16 + l) * 32 + swr * 8);
    }
#pragma unroll
    for (int i = 0; i < 4; i++)
#pragma unroll
      for (int j = 0; j < 4; j++) {
        acc[i][j] = __builtin_amdgcn_mfma_f32_16x16x32_bf16(af0[i], bf0[j], acc[i][j], 0, 0, 0);
        acc[i][j] = __builtin_amdgcn_mfma_f32_16x16x32_bf16(af1[i], bf1[j], acc[i][j], 0, 0, 0);
      }
    __syncthreads();
  }
  // LDS-staged coalesced store
  bf16* stage = (bf16*)base;
#pragma unroll
  for (int ph = 0; ph < 2; ph++) {
    if (wm == ph * 64) {
#pragma unroll
      for (int i = 0; i < 4; i++)
#pragma unroll
        for (int j = 0; j < 4; j++)
#pragma unroll
          for (int r = 0; r < 4; r++)
            stage[(i * 16 + q * 4 + r) * SROW_ + wn + j * 16 + l] = (bf16)acc[i][j][r];
    }
    __syncthreads();
#pragma unroll
    for (int pass = 0; pass < 4; pass++) {
      int u = pass * 256 + stid;
      int row = u >> 4, seg = u & 15;
      bf16x8 v = *(const bf16x8*)(stage + row * SROW_ + seg * 8);
      *(bf16x8*)(C + (m0 + ph * 64 + row) * (long)H_ + n0 + seg * 8) = v;
    }
    __syncthreads();
  }
}

// layer-1 tile with fused embedding gather; mtile -> (trow, b0); K=128 (padded E)
__device__ __forceinline__ void gemm_tile_embed(
    const int* __restrict__ tokens, const float* __restrict__ emb,
    const bf16* __restrict__ Bt, bf16* __restrict__ xwc, int t0,
    int mtile, int ntile, int stid, char* base) {
  bf16* As0 = (bf16*)base;
  bf16* Bs0 = (bf16*)(base + 8192);
  bf16* As1 = (bf16*)(base + 16384);
  bf16* Bs1 = (bf16*)(base + 24576);
  int* stok = (int*)(base + 32768);
  const int K = 128;
  const int wave = stid >> 6, lane = stid & 63;
  const int l = lane & 15, q = lane >> 4;
  const int trow = mtile >> 4;
  const int b0 = (mtile & 15) * 128;
  const int t = t0 + trow;
  const int n0 = ntile * 128;
  const int wm = (wave >> 1) * 64, wn = (wave & 1) * 64;

  if (stid < 128) stok[stid] = tokens[(b0 + stid) * T_ + t];
  __syncthreads();

  f32x4 acc[4][4] = {};

  const int e0 = stid, e1 = 256 + stid;
  const int r0 = e0 >> 2, c0 = e0 & 3;
  const int r1 = e1 >> 2, c1 = e1 & 3;
  const int s0 = c0 ^ (r0 & 3) ^ ((r0 >> 2) & 3);
  const int s1 = c1 ^ (r1 & 3) ^ ((r1 >> 2) & 3);
  const int swr = q ^ (l & 3) ^ ((l >> 2) & 3);

  const bf16* B0 = Bt + (long)(n0 + r0) * K + s0 * 8;
  const bf16* B1 = Bt + (long)(n0 + r1) * K + s1 * 8;
  const int w0o = (wave * 64) * 8, w1o = (256 + wave * 64) * 8;

  const int ar = stid >> 1, hh = stid & 1;
  const int asw = (ar & 3) ^ ((ar >> 2) & 3);
  const float* er = emb + (long)stok[ar] * E_;

  for (int k0 = 0; k0 < K; k0 += 64) {
    __builtin_amdgcn_global_load_lds((const AS1 void*)(B0 + k0), (AS3 void*)(Bs0 + w0o), 16, 0, 0);
    __builtin_amdgcn_global_load_lds((const AS1 void*)(B1 + k0), (AS3 void*)(Bs0 + w1o), 16, 0, 0);
    __builtin_amdgcn_global_load_lds((const AS1 void*)(B0 + k0 + 32), (AS3 void*)(Bs1 + w0o), 16, 0, 0);
    __builtin_amdgcn_global_load_lds((const AS1 void*)(B1 + k0 + 32), (AS3 void*)(Bs1 + w1o), 16, 0, 0);
#pragma unroll
    for (int set = 0; set < 2; set++) {
      bf16* Asx = set ? As1 : As0;
      int kb0 = k0 + set * 32;
      bf16x8 v[2];
#pragma unroll
      for (int cch = 0; cch < 2; cch++) {
        int kb = kb0 + hh * 16 + cch * 8;
#pragma unroll
        for (int j = 0; j < 8; j++) {
          int k = kb + j;
          v[cch][j] = (bf16)((k < E_) ? er[k] : 0.f);
        }
      }
      *(bf16x8*)(Asx + ar * 32 + ((2 * hh + 0) ^ asw) * 8) = v[0];
      *(bf16x8*)(Asx + ar * 32 + ((2 * hh + 1) ^ asw) * 8) = v[1];
    }
    __syncthreads();
    bf16x8 af0[4], bf0[4], af1[4], bf1[4];
#pragma unroll
    for (int i = 0; i < 4; i++) {
      af0[i] = *(const bf16x8*)(As0 + (wm + i * 16 + l) * 32 + swr * 8);
      bf0[i] = *(const bf16x8*)(Bs0 + (wn + i * 16 + l) * 32 + swr * 8);
      af1[i] = *(const bf16x8*)(As1 + (wm + i * 16 + l) * 32 + swr * 8);
      bf1[i] = *(const bf16x8*)(Bs1 + (wn + i * 16 + l) * 32 + swr * 8);
    }
#pragma unroll
    for (int i = 0; i < 4; i++)
#pragma unroll
      for (int j = 0; j < 4; j++) {
        acc[i][j] = __builtin_amdgcn_mfma_f32_16x16x32_bf16(af0[i], bf0[j], acc[i][j], 0, 0, 0);
        acc[i][j] = __builtin_amdgcn_mfma_f32_16x16x32_bf16(af1[i], bf1[j], acc[i][j], 0, 0, 0);
      }
    __syncthreads();
  }
  // LDS-staged coalesced store
  bf16* C = xwc + ((long)trow * B_ + b0) * H_;
  bf16* stage = (bf16*)base;
#pragma unroll
  for (int ph = 0; ph < 2; ph++) {
    if (wm == ph * 64) {
#pragma unroll
      for (int i = 0; i < 4; i++)
#pragma unroll
        for (int j = 0; j < 4; j++)
#pragma unroll
          for (int r = 0; r < 4; r++)
            stage[(i * 16 + q * 4 + r) * SROW_ + wn + j * 16 + l] = (bf16)acc[i][j][r];
    }
    __syncthreads();
#pragma unroll
    for (int pass = 0; pass < 4; pass++) {
      int u = pass * 256 + stid;
      int row = u >> 4, seg = u & 15;
      bf16x8 v = *(const bf16x8*)(stage + row * SROW_ + seg * 8);
      *(bf16x8*)(C + (long)(ph * 64 + row) * H_ + n0 + seg * 8) = v;
    }
    __syncthreads();
  }
}

struct GemmTasks {
  const bf16* A[4];
  const bf16* Bt[4];
  bf16* C[4];
  int kind[4];
  int t0[4];
};

// 512 tiles per task; block -> (task, tile)
__global__ __launch_bounds__(256) void gemm_multi(
    GemmTasks gt, const int* __restrict__ tokens, const float* __restrict__ emb) {
  __shared__ __align__(16) char smem[33280];
  const int task = blockIdx.x >> 9;
  const int tile = blockIdx.x & 511;
  const int mt = tile & 127, ntl = tile >> 7;
  if (gt.kind[task] == 1)
    gemm_tile_embed(tokens, emb, gt.Bt[task], gt.C[task], gt.t0[task], mt, ntl,
                    threadIdx.x, smem);
  else
    gemm_tile(gt.A[task], gt.Bt[task], gt.C[task], mt, ntl, threadIdx.x, smem);
}

struct RnnTasks {
  const bf16* xwc[4];
  const unsigned char* U8[4];
  const float* bias[4];
  int t0[4];
  int first[4];
};

// Multi-task recurrent chunk: 64 blocks/task x 512 thr (8 waves; LDS 99.8KB ->
// 1 block/CU -> 2 waves/SIMD). __launch_bounds__(512,1) grants a >=256-reg/lane
// budget so Ureg[8][4] (128 VGPRs = the wave's FULL 32KB U slice) is truly
// register-resident — zero per-step U traffic (R16-20 evidence: 1024-thr shapes
// get a ~64-reg default budget and silently spill Ureg to scratch).
// wave = 4 hidden-tiles x 32 batch. h fp8 double-buffered LDS; xw 2-buf async
// staging, buffer reused for bf16 h out -> coalesced b128 seq stores; one
// barrier/step.
__global__ __launch_bounds__(512, 1) void rnn_multi(RnnTasks rt, bf16* __restrict__ seq) {
  __shared__ __align__(16) char smem[99840];
  char* hls8 = smem;                    // 2 x (32 x 520 B) fp8 h
  bf16* xws = (bf16*)(smem + 33280);    // 2 x (32 x 520) bf16: xw in / h out
  const int task = blockIdx.x >> 6;
  const int blk = blockIdx.x & 63;
  const bf16* xwc = rt.xwc[task];
  const unsigned char* U8 = rt.U8[task];
  const float* bias = rt.bias[task];
  const int t0 = rt.t0[task];
  const int first = rt.first[task];
  const int tid = threadIdx.x;
  const int wave = tid >> 6, lane = tid & 63;
  const int l = lane & 15, q = lane >> 4;
  const int b0 = blk * ROWS_;

  // preload this wave's U slice: hidden-tiles wave*4 .. wave*4+3 (32 KB/wave)
  const unsigned char* Ub = U8 + (long)(wave * 4) * 8192 + lane * 16;
  u64x2 Ureg[8][4];
#pragma unroll
  for (int kk2 = 0; kk2 < 8; kk2++)
#pragma unroll
    for (int nt = 0; nt < 4; nt++)
      Ureg[kk2][nt] = *(const u64x2*)(Ub + nt * 8192 + kk2 * 1024);

  // init h_{t0-1} into hls8[0]: wave handles rows wave*4 .. +3
#pragma unroll
  for (int rr = 0; rr < 4; rr++) {
    int m = wave * 4 + rr;
    long pk = 0;
    if (!first) {
      const bf16* hsrc = seq + ((long)(t0 - 1) * B_ + b0 + m) * H_;
      bf16x8 v = *(const bf16x8*)(hsrc + lane * 8);
      float f[8];
#pragma unroll
      for (int j = 0; j < 8; j++) f[j] = (float)v[j] * 16.f;
      pk = pack_fp8x8(f);
    }
    *(long*)(hls8 + m * 520 + lane * 8) = pk;
  }

  // bias indexed by hidden = (wave*4+nt)*16 + q*4 + r
  float bb[4][4];
#pragma unroll
  for (int nt = 0; nt < 4; nt++)
#pragma unroll
    for (int r = 0; r < 4; r++)
      bb[nt][r] = bias[(wave * 4 + nt) * 16 + q * 4 + r];

  auto prefetch = [&](int tl2) {
    int buf = tl2 & 1;
#pragma unroll
    for (int rr = 0; rr < 4; rr++) {
      int row = wave * 4 + rr;
      __builtin_amdgcn_global_load_lds(
          (const AS1 void*)(xwc + ((long)tl2 * B_ + b0 + row) * H_ + lane * 8),
          (AS3 void*)(xws + (buf * ROWS_ + row) * 520), 16, 0, 0);
    }
  };

  prefetch(0);
  __syncthreads();  // xws buf 0 ready; hls8[0] visible

  for (int tl = 0; tl < TC_; tl++) {
    // store h(tl-1) from xws[(tl-1)&1] (ds_reads before the DMA into same rows)
    if (tl > 0) {
      const bf16* src = xws + (((tl - 1) & 1) * ROWS_) * 520;
      bf16* sp = seq + ((long)(t0 + tl - 1) * B_ + b0) * H_;
#pragma unroll
      for (int rr = 0; rr < 4; rr++) {
        int m = wave * 4 + rr;
        *(bf16x8*)(sp + (long)m * H_ + lane * 8) =
            *(const bf16x8*)(src + m * 520 + lane * 8);
      }
    }
    if (tl + 1 < TC_) prefetch(tl + 1);  // lands by this step's barrier

    const char* hb0 = hls8 + ((tl & 1) * ROWS_ + l) * 520 + q * 8;
    const char* hb1 = hb0 + 16 * 520;
    f32x4 acc[4][2] = {};
#pragma unroll
    for (int kk2 = 0; kk2 < 8; kk2++) {
      long h0a = *(const long*)(hb0 + kk2 * 64);
      long h0b = *(const long*)(hb0 + kk2 * 64 + 32);
      long h1a = *(const long*)(hb1 + kk2 * 64);
      long h1b = *(const long*)(hb1 + kk2 * 64 + 32);
#pragma unroll
      for (int nt = 0; nt < 4; nt++) {
        acc[nt][0] = __builtin_amdgcn_mfma_f32_16x16x32_fp8_fp8((long)Ureg[kk2][nt].x, h0a,
                                                                acc[nt][0], 0, 0, 0);
        acc[nt][1] = __builtin_amdgcn_mfma_f32_16x16x32_fp8_fp8((long)Ureg[kk2][nt].x, h1a,
                                                                acc[nt][1], 0, 0, 0);
        acc[nt][0] = __builtin_amdgcn_mfma_f32_16x16x32_fp8_fp8((long)Ureg[kk2][nt].y, h0b,
                                                                acc[nt][0], 0, 0, 0);
        acc[nt][1] = __builtin_amdgcn_mfma_f32_16x16x32_fp8_fp8((long)Ureg[kk2][nt].y, h1b,
                                                                acc[nt][1], 0, 0, 0);
      }
    }
    // epilogue: D col=batch, row=4 consecutive hiddens; read xw then overwrite
    // the same xws slots with bf16 h (same thread, same addresses)
#pragma unroll
    for (int nt = 0; nt < 4; nt++) {
      int hoff = (wave * 4 + nt) * 16 + q * 4;
#pragma unroll
      for (int bh = 0; bh < 2; bh++) {
        bf16* xp = xws + ((tl & 1) * ROWS_ + bh * 16 + l) * 520 + hoff;
        bf16x4 xv = *(const bf16x4*)xp;
        float hv[4];
#pragma unroll
        for (int r = 0; r < 4; r++)
          hv[r] = fast_tanh((float)xv[r] + bb[nt][r] + acc[nt][bh][r] * 0.0009765625f);
        unsigned pw = (unsigned)__builtin_amdgcn_cvt_pk_fp8_f32(
            hv[0] * 16.f, hv[1] * 16.f, 0, false);
        pw = (unsigned)__builtin_amdgcn_cvt_pk_fp8_f32(
            hv[2] * 16.f, hv[3] * 16.f, (int)pw, true);
        *(unsigned*)(hls8 + (((tl + 1) & 1) * ROWS_ + bh * 16 + l) * 520 + hoff) = pw;
        bf16x4 h4;
#pragma unroll
        for (int r = 0; r < 4; r++) h4[r] = (bf16)hv[r];
        *(bf16x4*)xp = h4;
      }
    }
    __syncthreads();  // one barrier/step
  }
  // final step's store
  {
    const bf16* src = xws + (((TC_ - 1) & 1) * ROWS_) * 520;
    bf16* sp = seq + ((long)(t0 + TC_ - 1) * B_ + b0) * H_;
#pragma unroll
    for (int rr = 0; rr < 4; rr++) {
      int m = wave * 4 + rr;
      *(bf16x8*)(sp + (long)m * H_ + lane * 8) =
          *(const bf16x8*)(src + m * 520 + lane * 8);
    }
  }
}

// out[b] = sigmoid(dot(seq[(T-1)*B + b, :], Wo) + bo)
__global__ __launch_bounds__(256) void head_kernel(
    const bf16* __restrict__ seq, const float* __restrict__ Wo,
    const float* __restrict__ bo, float* __restrict__ out) {
  int wave = threadIdx.x >> 6, lane = threadIdx.x & 63;
  int row = blockIdx.x * 4 + wave;
  const bf16* p = seq + ((long)(T_ - 1) * B_ + row) * H_ + lane * 8;
  bf16x8 v = *(const bf16x8*)p;
  float s = 0.f;
#pragma unroll
  for (int i = 0; i < 8; i++) s += (float)v[i] * Wo[lane * 8 + i];
#pragma unroll
  for (int off = 32; off; off >>= 1) s += __shfl_down(s, off, 64);
  if (lane == 0) {
    float x = s + bo[0];
    out[row] = 1.f / (1.f + exp2f(-x * 1.44269504088896f));
  }
}

extern "C" void kernel_launch(void* const* d_in, const int* in_sizes, int n_in,
                              void* d_out, int out_size, void* d_ws, size_t ws_size,
                              hipStream_t stream) {
  (void)in_sizes; (void)n_in; (void)out_size;
  const int*   tokens = (const int*)d_in[0];
  const float* emb = (const float*)d_in[1];
  const float* Ws[4] = {(const float*)d_in[2], (const float*)d_in[5],
                        (const float*)d_in[8], (const float*)d_in[11]};
  const float* Us[4] = {(const float*)d_in[3], (const float*)d_in[6],
                        (const float*)d_in[9], (const float*)d_in[12]};
  const float* bs[4] = {(const float*)d_in[4], (const float*)d_in[7],
                        (const float*)d_in[10], (const float*)d_in[13]};
  const float* Wo = (const float*)d_in[14];
  const float* bo = (const float*)d_in[15];
  float* out = (float*)d_out;

  char* w = (char*)d_ws;
  const size_t SEQ_BYTES = (size_t)T_ * B_ * H_ * 2;           // 160 MB
  const size_t WEIGHTS = (512 * 128 + 3 * 512 * 512) * 2 + 4 * 512 * 512;
  const size_t XWB = (size_t)TC_ * B_ * H_ * 2;                // 16 MB
  const bool wf = ws_size >= SEQ_BYTES + WEIGHTS + 4 * XWB;    // ~227.4 MB

  bf16* SEQ = (bf16*)w;
  char* wb = w + SEQ_BYTES;
  bf16* Wt[4];
  Wt[0] = (bf16*)wb;
  Wt[1] = Wt[0] + 512 * 128;
  Wt[2] = Wt[1] + 512 * 512;
  Wt[3] = Wt[2] + 512 * 512;
  unsigned char* Up[4];
  Up[0] = (unsigned char*)(Wt[3] + 512 * 512);
  Up[1] = Up[0] + 512 * 512;
  Up[2] = Up[1] + 512 * 512;
  Up[3] = Up[2] + 512 * 512;
  char* bankbase = w + SEQ_BYTES + WEIGHTS;
  bf16* BANK[4];
  for (int i = 0; i < 4; i++) BANK[i] = (bf16*)(bankbase + (size_t)i * XWB);

  {
    WConv wc{};
    UConv uc{};
    for (int i = 0; i < 4; i++) {
      wc.src[i] = Ws[i]; wc.dst[i] = Wt[i];
      wc.K[i] = (i == 0) ? 100 : 512;
      wc.Kp[i] = (i == 0) ? 128 : 512;
      uc.src[i] = Us[i]; uc.dst[i] = Up[i];
    }
    convert_weight_all<<<dim3(1024, 4), 256, 0, stream>>>(wc);
    convert_u_all<<<dim3(128, 4), 256, 0, stream>>>(uc);
  }

  if (wf) {
    // layer-wavefront: round r = gemm then rnn for tasks (l, c=r-l), bank per layer.
    for (int r = 0; r <= NC_ - 1 + L_ - 1; r++) {
      GemmTasks gt{};
      RnnTasks rt{};
      int n = 0;
      int lmin = r - (NC_ - 1); if (lmin < 0) lmin = 0;
      int lmax = r < L_ - 1 ? r : L_ - 1;
      for (int l = lmin; l <= lmax; l++) {
        int c = r - l;
        bf16* xb = BANK[l];
        gt.A[n] = SEQ + (size_t)c * TC_ * B_ * H_;
        gt.Bt[n] = Wt[l];
        gt.C[n] = xb;
        gt.kind[n] = (l == 0) ? 1 : 2;
        gt.t0[n] = c * TC_;
        rt.xwc[n] = xb;
        rt.U8[n] = Up[l];
        rt.bias[n] = bs[l];
        rt.t0[n] = c * TC_;
        rt.first[n] = (c == 0) ? 1 : 0;
        n++;
      }
      gemm_multi<<<n * 512, 256, 0, stream>>>(gt, tokens, emb);
      rnn_multi<<<n * 64, 512, 0, stream>>>(rt, SEQ);
    }
  } else {
    // serial fallback: 2 banks
    for (int l = 0; l < L_; l++) {
      for (int c = 0; c < NC_; c++) {
        bf16* xb = BANK[c & 1];
        GemmTasks gt{};
        RnnTasks rt{};
        gt.A[0] = SEQ + (size_t)c * TC_ * B_ * H_;
        gt.Bt[0] = Wt[l];
        gt.C[0] = xb;
        gt.kind[0] = (l == 0) ? 1 : 2;
        gt.t0[0] = c * TC_;
        rt.xwc[0] = xb;
        rt.U8[0] = Up[l];
        rt.bias[0] = bs[l];
        rt.t0[0] = c * TC_;
        rt.first[0] = (c == 0) ? 1 : 0;
        gemm_multi<<<512, 256, 0, stream>>>(gt, tokens, emb);
        rnn_multi<<<64, 512, 0, stream>>>(rt, SEQ);
      }
    }
  }

  head_kernel<<<B_ / 4, 256, 0, stream>>>(SEQ, Wo, bo, out);
}

// Round 22
// 1010.521 us; speedup vs baseline: 4.6532x; 1.0351x over previous
//
#include <hip/hip_runtime.h>

typedef __bf16 bf16;
typedef bf16 bf16x4 __attribute__((ext_vector_type(4)));
typedef bf16 bf16x8 __attribute__((ext_vector_type(8)));
typedef float f32x4 __attribute__((ext_vector_type(4)));
typedef unsigned long u64x2 __attribute__((ext_vector_type(2)));

#define AS1 __attribute__((address_space(1)))
#define AS3 __attribute__((address_space(3)))

#define B_ 2048
#define T_ 80
#define E_ 100
#define H_ 512
#define TC_ 8               // time-chunk
#define NC_ (T_ / TC_)      // 10 chunks
#define ROWS_ 32            // batch rows per rnn block (64 blocks/task)
#define L_ 4

// SEQ is TIME-MAJOR: seq[(t*B_ + b)*H_ + h]
// U fp8 A-OPERAND layout (operand-swapped rnn: D = (h@U)^T = mfma(A=U^T, B=h)):
//   hidden-tile ht, kk-pair p -> 1024B block at (ht*8+p)*1024;
//   byte[lane*16 + half*8 + j] = U[k=(2p+half)*32+(lane>>4)*8+j][ht*16+(lane&15)] * 2^6

__device__ __forceinline__ float fast_tanh(float x) {
  float e = exp2f(x * 2.8853900817779268f);  // e^{2x}
  return 1.f - 2.f * __builtin_amdgcn_rcpf(e + 1.f);
}

__device__ __forceinline__ long pack_fp8x8(const float* f) {
  int w0 = __builtin_amdgcn_cvt_pk_fp8_f32(f[0], f[1], 0, false);
  w0 = __builtin_amdgcn_cvt_pk_fp8_f32(f[2], f[3], w0, true);
  int w1 = __builtin_amdgcn_cvt_pk_fp8_f32(f[4], f[5], 0, false);
  w1 = __builtin_amdgcn_cvt_pk_fp8_f32(f[6], f[7], w1, true);
  return (long)(((unsigned long)(unsigned)w1 << 32) | (unsigned)w0);
}

// ---- Merged weight conversion (2 launches) ----

struct WConv {
  const float* src[4];
  bf16* dst[4];
  int K[4];
  int Kp[4];
};

__global__ void convert_weight_all(WConv wc) {
  int layer = blockIdx.y;
  int idx = blockIdx.x * 256 + threadIdx.x;
  int K = wc.K[layer], Kp = wc.Kp[layer];
  if (idx >= 512 * Kp) return;
  int n = idx / Kp, k = idx - n * Kp;
  float v = (k < K) ? wc.src[layer][(long)k * 512 + n] : 0.f;
  wc.dst[layer][idx] = (bf16)v;
}

struct UConv {
  const float* src[4];
  unsigned char* dst[4];
};

__global__ void convert_u_all(UConv uc) {
  int layer = blockIdx.y;
  int idx = blockIdx.x * 256 + threadIdx.x;
  int half = idx & 1, lane = (idx >> 1) & 63, p = (idx >> 7) & 7, ht = idx >> 10;
  int q = lane >> 4;
  int k0 = (2 * p + half) * 32 + q * 8;
  int n = ht * 16 + (lane & 15);
  float f[8];
#pragma unroll
  for (int j = 0; j < 8; j++) f[j] = uc.src[layer][(long)(k0 + j) * H_ + n] * 64.f;
  *(long*)(uc.dst[layer] + (long)(ht * 8 + p) * 1024 + lane * 16 + half * 8) = pack_fp8x8(f);
}

// ---- GEMM tile device functions (256-thread block, 66048B LDS) ----
// BK=64, double-buffered: loads for iter i+1 issue before compute of iter i.

#define SROW_ 136  // stage row stride in bf16 (272 B)

__device__ __forceinline__ void gemm_tile(
    const bf16* __restrict__ A, const bf16* __restrict__ Bt, bf16* __restrict__ C,
    int mtile, int ntile, int stid, char* base) {
  const int K = 512;
  const int wave = stid >> 6, lane = stid & 63;
  const int l = lane & 15, q = lane >> 4;
  const long m0 = (long)mtile * 128;
  const int n0 = ntile * 128;
  const int wm = (wave >> 1) * 64, wn = (wave & 1) * 64;

  f32x4 acc[4][4] = {};

  const int e0 = stid, e1 = 256 + stid;
  const int r0 = e0 >> 2, c0 = e0 & 3;
  const int r1 = e1 >> 2, c1 = e1 & 3;
  const int s0 = c0 ^ (r0 & 3) ^ ((r0 >> 2) & 3);
  const int s1 = c1 ^ (r1 & 3) ^ ((r1 >> 2) & 3);
  const int swr = q ^ (l & 3) ^ ((l >> 2) & 3);

  const bf16* A0 = A + (m0 + r0) * K + s0 * 8;
  const bf16* A1 = A + (m0 + r1) * K + s1 * 8;
  const bf16* B0 = Bt + (long)(n0 + r0) * K + s0 * 8;
  const bf16* B1 = Bt + (long)(n0 + r1) * K + s1 * 8;
  const int w0o = (wave * 64) * 8, w1o = (256 + wave * 64) * 8;

  auto issue = [&](int i) {  // stage K-block [i*64, i*64+64) into buf[i&1]
    char* bb = base + (i & 1) * 32768;
    bf16* As0 = (bf16*)bb;
    bf16* Bs0 = (bf16*)(bb + 8192);
    bf16* As1 = (bf16*)(bb + 16384);
    bf16* Bs1 = (bf16*)(bb + 24576);
    int k0 = i * 64;
    __builtin_amdgcn_global_load_lds((const AS1 void*)(A0 + k0), (AS3 void*)(As0 + w0o), 16, 0, 0);
    __builtin_amdgcn_global_load_lds((const AS1 void*)(A1 + k0), (AS3 void*)(As0 + w1o), 16, 0, 0);
    __builtin_amdgcn_global_load_lds((const AS1 void*)(B0 + k0), (AS3 void*)(Bs0 + w0o), 16, 0, 0);
    __builtin_amdgcn_global_load_lds((const AS1 void*)(B1 + k0), (AS3 void*)(Bs0 + w1o), 16, 0, 0);
    __builtin_amdgcn_global_load_lds((const AS1 void*)(A0 + k0 + 32), (AS3 void*)(As1 + w0o), 16, 0, 0);
    __builtin_amdgcn_global_load_lds((const AS1 void*)(A1 + k0 + 32), (AS3 void*)(As1 + w1o), 16, 0, 0);
    __builtin_amdgcn_global_load_lds((const AS1 void*)(B0 + k0 + 32), (AS3 void*)(Bs1 + w0o), 16, 0, 0);
    __builtin_amdgcn_global_load_lds((const AS1 void*)(B1 + k0 + 32), (AS3 void*)(Bs1 + w1o), 16, 0, 0);
  };

  issue(0);
  __syncthreads();  // buf0 ready
  for (int i = 0; i < 8; i++) {
    if (i + 1 < 8) issue(i + 1);  // overlaps compute below; drains at barrier
    char* bb = base + (i & 1) * 32768;
    bf16* As0 = (bf16*)bb;
    bf16* Bs0 = (bf16*)(bb + 8192);
    bf16* As1 = (bf16*)(bb + 16384);
    bf16* Bs1 = (bf16*)(bb + 24576);
    bf16x8 af0[4], bf0[4], af1[4], bf1[4];
#pragma unroll
    for (int i2 = 0; i2 < 4; i2++) {
      af0[i2] = *(const bf16x8*)(As0 + (wm + i2 * 16 + l) * 32 + swr * 8);
      bf0[i2] = *(const bf16x8*)(Bs0 + (wn + i2 * 16 + l) * 32 + swr * 8);
      af1[i2] = *(const bf16x8*)(As1 + (wm + i2 * 16 + l) * 32 + swr * 8);
      bf1[i2] = *(const bf16x8*)(Bs1 + (wn + i2 * 16 + l) * 32 + swr * 8);
    }
#pragma unroll
    for (int i2 = 0; i2 < 4; i2++)
#pragma unroll
      for (int j = 0; j < 4; j++) {
        acc[i2][j] = __builtin_amdgcn_mfma_f32_16x16x32_bf16(af0[i2], bf0[j], acc[i2][j], 0, 0, 0);
        acc[i2][j] = __builtin_amdgcn_mfma_f32_16x16x32_bf16(af1[i2], bf1[j], acc[i2][j], 0, 0, 0);
      }
    __syncthreads();  // drains issue(i+1); protects buf reuse
  }
  // LDS-staged coalesced store
  bf16* stage = (bf16*)base;
#pragma unroll
  for (int ph = 0; ph < 2; ph++) {
    if (wm == ph * 64) {
#pragma unroll
      for (int i = 0; i < 4; i++)
#pragma unroll
        for (int j = 0; j < 4; j++)
#pragma unroll
          for (int r = 0; r < 4; r++)
            stage[(i * 16 + q * 4 + r) * SROW_ + wn + j * 16 + l] = (bf16)acc[i][j][r];
    }
    __syncthreads();
#pragma unroll
    for (int pass = 0; pass < 4; pass++) {
      int u = pass * 256 + stid;
      int row = u >> 4, seg = u & 15;
      bf16x8 v = *(const bf16x8*)(stage + row * SROW_ + seg * 8);
      *(bf16x8*)(C + (m0 + ph * 64 + row) * (long)H_ + n0 + seg * 8) = v;
    }
    __syncthreads();
  }
}

// layer-1 tile with fused embedding gather; K=128 (2 BK=64 iters), same pipeline
__device__ __forceinline__ void gemm_tile_embed(
    const int* __restrict__ tokens, const float* __restrict__ emb,
    const bf16* __restrict__ Bt, bf16* __restrict__ xwc, int t0,
    int mtile, int ntile, int stid, char* base) {
  int* stok = (int*)(base + 65536);
  const int K = 128;
  const int wave = stid >> 6, lane = stid & 63;
  const int l = lane & 15, q = lane >> 4;
  const int trow = mtile >> 4;
  const int b0 = (mtile & 15) * 128;
  const int t = t0 + trow;
  const int n0 = ntile * 128;
  const int wm = (wave >> 1) * 64, wn = (wave & 1) * 64;

  if (stid < 128) stok[stid] = tokens[(b0 + stid) * T_ + t];
  __syncthreads();

  f32x4 acc[4][4] = {};

  const int e0 = stid, e1 = 256 + stid;
  const int r0 = e0 >> 2, c0 = e0 & 3;
  const int r1 = e1 >> 2, c1 = e1 & 3;
  const int s0 = c0 ^ (r0 & 3) ^ ((r0 >> 2) & 3);
  const int s1 = c1 ^ (r1 & 3) ^ ((r1 >> 2) & 3);
  const int swr = q ^ (l & 3) ^ ((l >> 2) & 3);

  const bf16* B0 = Bt + (long)(n0 + r0) * K + s0 * 8;
  const bf16* B1 = Bt + (long)(n0 + r1) * K + s1 * 8;
  const int w0o = (wave * 64) * 8, w1o = (256 + wave * 64) * 8;

  const int ar = stid >> 1, hh = stid & 1;
  const int asw = (ar & 3) ^ ((ar >> 2) & 3);
  const float* er = emb + (long)stok[ar] * E_;

  auto issue = [&](int i) {  // B loads + A emb-gather for K-block i into buf[i&1]
    char* bb = base + (i & 1) * 32768;
    bf16* Bs0 = (bf16*)(bb + 8192);
    bf16* Bs1 = (bf16*)(bb + 24576);
    int k0 = i * 64;
    __builtin_amdgcn_global_load_lds((const AS1 void*)(B0 + k0), (AS3 void*)(Bs0 + w0o), 16, 0, 0);
    __builtin_amdgcn_global_load_lds((const AS1 void*)(B1 + k0), (AS3 void*)(Bs0 + w1o), 16, 0, 0);
    __builtin_amdgcn_global_load_lds((const AS1 void*)(B0 + k0 + 32), (AS3 void*)(Bs1 + w0o), 16, 0, 0);
    __builtin_amdgcn_global_load_lds((const AS1 void*)(B1 + k0 + 32), (AS3 void*)(Bs1 + w1o), 16, 0, 0);
#pragma unroll
    for (int set = 0; set < 2; set++) {
      bf16* Asx = (bf16*)(bb + set * 16384);
      int kb0 = k0 + set * 32;
      bf16x8 v[2];
#pragma unroll
      for (int cch = 0; cch < 2; cch++) {
        int kb = kb0 + hh * 16 + cch * 8;
#pragma unroll
        for (int j = 0; j < 8; j++) {
          int k = kb + j;
          v[cch][j] = (bf16)((k < E_) ? er[k] : 0.f);
        }
      }
      *(bf16x8*)(Asx + ar * 32 + ((2 * hh + 0) ^ asw) * 8) = v[0];
      *(bf16x8*)(Asx + ar * 32 + ((2 * hh + 1) ^ asw) * 8) = v[1];
    }
  };

  issue(0);
  __syncthreads();
  for (int i = 0; i < 2; i++) {
    if (i + 1 < 2) issue(i + 1);
    char* bb = base + (i & 1) * 32768;
    bf16* As0 = (bf16*)bb;
    bf16* Bs0 = (bf16*)(bb + 8192);
    bf16* As1 = (bf16*)(bb + 16384);
    bf16* Bs1 = (bf16*)(bb + 24576);
    bf16x8 af0[4], bf0[4], af1[4], bf1[4];
#pragma unroll
    for (int i2 = 0; i2 < 4; i2++) {
      af0[i2] = *(const bf16x8*)(As0 + (wm + i2 * 16 + l) * 32 + swr * 8);
      bf0[i2] = *(const bf16x8*)(Bs0 + (wn + i2 * 16 + l) * 32 + swr * 8);
      af1[i2] = *(const bf16x8*)(As1 + (wm + i2 * 16 + l) * 32 + swr * 8);
      bf1[i2] = *(const bf16x8*)(Bs1 + (wn + i2 * 16 + l) * 32 + swr * 8);
    }
#pragma unroll
    for (int i2 = 0; i2 < 4; i2++)
#pragma unroll
      for (int j = 0; j < 4; j++) {
        acc[i2][j] = __builtin_amdgcn_mfma_f32_16x16x32_bf16(af0[i2], bf0[j], acc[i2][j], 0, 0, 0);
        acc[i2][j] = __builtin_amdgcn_mfma_f32_16x16x32_bf16(af1[i2], bf1[j], acc[i2][j], 0, 0, 0);
      }
    __syncthreads();
  }
  // LDS-staged coalesced store
  bf16* C = xwc + ((long)trow * B_ + b0) * H_;
  bf16* stage = (bf16*)base;
#pragma unroll
  for (int ph = 0; ph < 2; ph++) {
    if (wm == ph * 64) {
#pragma unroll
      for (int i = 0; i < 4; i++)
#pragma unroll
        for (int j = 0; j < 4; j++)
#pragma unroll
          for (int r = 0; r < 4; r++)
            stage[(i * 16 + q * 4 + r) * SROW_ + wn + j * 16 + l] = (bf16)acc[i][j][r];
    }
    __syncthreads();
#pragma unroll
    for (int pass = 0; pass < 4; pass++) {
      int u = pass * 256 + stid;
      int row = u >> 4, seg = u & 15;
      bf16x8 v = *(const bf16x8*)(stage + row * SROW_ + seg * 8);
      *(bf16x8*)(C + (long)(ph * 64 + row) * H_ + n0 + seg * 8) = v;
    }
    __syncthreads();
  }
}

struct GemmTasks {
  const bf16* A[4];
  const bf16* Bt[4];
  bf16* C[4];
  int kind[4];
  int t0[4];
};

// 512 tiles per task; block -> (task, tile)
__global__ __launch_bounds__(256) void gemm_multi(
    GemmTasks gt, const int* __restrict__ tokens, const float* __restrict__ emb) {
  __shared__ __align__(16) char smem[66048];
  const int task = blockIdx.x >> 9;
  const int tile = blockIdx.x & 511;
  const int mt = tile & 127, ntl = tile >> 7;
  if (gt.kind[task] == 1)
    gemm_tile_embed(tokens, emb, gt.Bt[task], gt.C[task], gt.t0[task], mt, ntl,
                    threadIdx.x, smem);
  else
    gemm_tile(gt.A[task], gt.Bt[task], gt.C[task], mt, ntl, threadIdx.x, smem);
}

struct RnnTasks {
  const bf16* xwc[4];
  const unsigned char* U8[4];
  const float* bias[4];
  int t0[4];
  int first[4];
};

// Multi-task recurrent chunk: 64 blocks/task x 1024 thr (16 waves = 4/SIMD);
// block = 32 batch rows; wave = 2 hidden-tiles x 32 batch.
// U preloaded to Ureg (compiler may stream from L2 — measured-best variant).
// h fp8 double-buffered LDS; xw 2-buf async staging, buffer reused for bf16 h
// out (read-then-write) -> coalesced b128 seq stores, one barrier/step.
__global__ __launch_bounds__(1024) void rnn_multi(RnnTasks rt, bf16* __restrict__ seq) {
  __shared__ __align__(16) char smem[99840];
  char* hls8 = smem;                    // 2 x (32 x 520 B) fp8 h
  bf16* xws = (bf16*)(smem + 33280);    // 2 x (32 x 520) bf16: xw in / h out
  const int task = blockIdx.x >> 6;
  const int blk = blockIdx.x & 63;
  const bf16* xwc = rt.xwc[task];
  const unsigned char* U8 = rt.U8[task];
  const float* bias = rt.bias[task];
  const int t0 = rt.t0[task];
  const int first = rt.first[task];
  const int tid = threadIdx.x;
  const int wave = tid >> 6, lane = tid & 63;
  const int l = lane & 15, q = lane >> 4;
  const int b0 = blk * ROWS_;

  // preload this wave's U slice into registers (hidden-tiles wave*2, wave*2+1)
  const unsigned char* Ub = U8 + (long)(wave * 2) * 8192 + lane * 16;
  u64x2 Ureg[8][2];
#pragma unroll
  for (int kk2 = 0; kk2 < 8; kk2++)
#pragma unroll
    for (int nt = 0; nt < 2; nt++)
      Ureg[kk2][nt] = *(const u64x2*)(Ub + nt * 8192 + kk2 * 1024);

  // init h_{t0-1} into hls8[0]: wave handles rows wave*2, wave*2+1
#pragma unroll
  for (int rr = 0; rr < 2; rr++) {
    int m = wave * 2 + rr;
    long pk = 0;
    if (!first) {
      const bf16* hsrc = seq + ((long)(t0 - 1) * B_ + b0 + m) * H_;
      bf16x8 v = *(const bf16x8*)(hsrc + lane * 8);
      float f[8];
#pragma unroll
      for (int j = 0; j < 8; j++) f[j] = (float)v[j] * 16.f;
      pk = pack_fp8x8(f);
    }
    *(long*)(hls8 + m * 520 + lane * 8) = pk;
  }

  // bias indexed by hidden = (wave*2+nt)*16 + q*4 + r
  float bb[2][4];
#pragma unroll
  for (int nt = 0; nt < 2; nt++)
#pragma unroll
    for (int r = 0; r < 4; r++)
      bb[nt][r] = bias[(wave * 2 + nt) * 16 + q * 4 + r];

  auto prefetch = [&](int tl2) {
    int buf = tl2 & 1;
#pragma unroll
    for (int rr = 0; rr < 2; rr++) {
      int row = wave * 2 + rr;
      __builtin_amdgcn_global_load_lds(
          (const AS1 void*)(xwc + ((long)tl2 * B_ + b0 + row) * H_ + lane * 8),
          (AS3 void*)(xws + (buf * ROWS_ + row) * 520), 16, 0, 0);
    }
  };

  prefetch(0);
  __syncthreads();  // xws buf 0 ready; hls8[0] visible

  for (int tl = 0; tl < TC_; tl++) {
    // store h(tl-1) from xws[(tl-1)&1] (ds_reads issued BEFORE the prefetch DMA
    // below targets the same buffer — keep this order)
    if (tl > 0) {
      const bf16* src = xws + (((tl - 1) & 1) * ROWS_) * 520;
      bf16* sp = seq + ((long)(t0 + tl - 1) * B_ + b0) * H_;
#pragma unroll
      for (int rr = 0; rr < 2; rr++) {
        int m = wave * 2 + rr;
        *(bf16x8*)(sp + (long)m * H_ + lane * 8) =
            *(const bf16x8*)(src + m * 520 + lane * 8);
      }
    }
    if (tl + 1 < TC_) prefetch(tl + 1);  // lands by this step's barrier

    const char* hb0 = hls8 + ((tl & 1) * ROWS_ + l) * 520 + q * 8;
    const char* hb1 = hb0 + 16 * 520;
    f32x4 acc[2][2] = {};
#pragma unroll
    for (int kk2 = 0; kk2 < 8; kk2++) {
      long h0a = *(const long*)(hb0 + kk2 * 64);
      long h0b = *(const long*)(hb0 + kk2 * 64 + 32);
      long h1a = *(const long*)(hb1 + kk2 * 64);
      long h1b = *(const long*)(hb1 + kk2 * 64 + 32);
#pragma unroll
      for (int nt = 0; nt < 2; nt++) {
        acc[nt][0] = __builtin_amdgcn_mfma_f32_16x16x32_fp8_fp8((long)Ureg[kk2][nt].x, h0a,
                                                                acc[nt][0], 0, 0, 0);
        acc[nt][1] = __builtin_amdgcn_mfma_f32_16x16x32_fp8_fp8((long)Ureg[kk2][nt].x, h1a,
                                                                acc[nt][1], 0, 0, 0);
        acc[nt][0] = __builtin_amdgcn_mfma_f32_16x16x32_fp8_fp8((long)Ureg[kk2][nt].y, h0b,
                                                                acc[nt][0], 0, 0, 0);
        acc[nt][1] = __builtin_amdgcn_mfma_f32_16x16x32_fp8_fp8((long)Ureg[kk2][nt].y, h1b,
                                                                acc[nt][1], 0, 0, 0);
      }
    }
    // epilogue: D col=batch, row=4 consecutive hiddens; read xw then overwrite
    // the same xws slots with bf16 h (same thread, same addresses)
#pragma unroll
    for (int nt = 0; nt < 2; nt++) {
      int hoff = (wave * 2 + nt) * 16 + q * 4;
#pragma unroll
      for (int bh = 0; bh < 2; bh++) {
        bf16* xp = xws + ((tl & 1) * ROWS_ + bh * 16 + l) * 520 + hoff;
        bf16x4 xv = *(const bf16x4*)xp;
        float hv[4];
#pragma unroll
        for (int r = 0; r < 4; r++)
          hv[r] = fast_tanh((float)xv[r] + bb[nt][r] + acc[nt][bh][r] * 0.0009765625f);
        unsigned pw = (unsigned)__builtin_amdgcn_cvt_pk_fp8_f32(
            hv[0] * 16.f, hv[1] * 16.f, 0, false);
        pw = (unsigned)__builtin_amdgcn_cvt_pk_fp8_f32(
            hv[2] * 16.f, hv[3] * 16.f, (int)pw, true);
        *(unsigned*)(hls8 + (((tl + 1) & 1) * ROWS_ + bh * 16 + l) * 520 + hoff) = pw;
        bf16x4 h4;
#pragma unroll
        for (int r = 0; r < 4; r++) h4[r] = (bf16)hv[r];
        *(bf16x4*)xp = h4;
      }
    }
    __syncthreads();  // one barrier/step
  }
  // final step's store
  {
    const bf16* src = xws + (((TC_ - 1) & 1) * ROWS_) * 520;
    bf16* sp = seq + ((long)(t0 + TC_ - 1) * B_ + b0) * H_;
#pragma unroll
    for (int rr = 0; rr < 2; rr++) {
      int m = wave * 2 + rr;
      *(bf16x8*)(sp + (long)m * H_ + lane * 8) =
          *(const bf16x8*)(src + m * 520 + lane * 8);
    }
  }
}

// out[b] = sigmoid(dot(seq[(T-1)*B + b, :], Wo) + bo)
__global__ __launch_bounds__(256) void head_kernel(
    const bf16* __restrict__ seq, const float* __restrict__ Wo,
    const float* __restrict__ bo, float* __restrict__ out) {
  int wave = threadIdx.x >> 6, lane = threadIdx.x & 63;
  int row = blockIdx.x * 4 + wave;
  const bf16* p = seq + ((long)(T_ - 1) * B_ + row) * H_ + lane * 8;
  bf16x8 v = *(const bf16x8*)p;
  float s = 0.f;
#pragma unroll
  for (int i = 0; i < 8; i++) s += (float)v[i] * Wo[lane * 8 + i];
#pragma unroll
  for (int off = 32; off; off >>= 1) s += __shfl_down(s, off, 64);
  if (lane == 0) {
    float x = s + bo[0];
    out[row] = 1.f / (1.f + exp2f(-x * 1.44269504088896f));
  }
}

extern "C" void kernel_launch(void* const* d_in, const int* in_sizes, int n_in,
                              void* d_out, int out_size, void* d_ws, size_t ws_size,
                              hipStream_t stream) {
  (void)in_sizes; (void)n_in; (void)out_size;
  const int*   tokens = (const int*)d_in[0];
  const float* emb = (const float*)d_in[1];
  const float* Ws[4] = {(const float*)d_in[2], (const float*)d_in[5],
                        (const float*)d_in[8], (const float*)d_in[11]};
  const float* Us[4] = {(const float*)d_in[3], (const float*)d_in[6],
                        (const float*)d_in[9], (const float*)d_in[12]};
  const float* bs[4] = {(const float*)d_in[4], (const float*)d_in[7],
                        (const float*)d_in[10], (const float*)d_in[13]};
  const float* Wo = (const float*)d_in[14];
  const float* bo = (const float*)d_in[15];
  float* out = (float*)d_out;

  char* w = (char*)d_ws;
  const size_t SEQ_BYTES = (size_t)T_ * B_ * H_ * 2;           // 160 MB
  const size_t WEIGHTS = (512 * 128 + 3 * 512 * 512) * 2 + 4 * 512 * 512;
  const size_t XWB = (size_t)TC_ * B_ * H_ * 2;                // 16 MB
  const bool wf = ws_size >= SEQ_BYTES + WEIGHTS + 4 * XWB;    // ~227.4 MB

  bf16* SEQ = (bf16*)w;
  char* wb = w + SEQ_BYTES;
  bf16* Wt[4];
  Wt[0] = (bf16*)wb;
  Wt[1] = Wt[0] + 512 * 128;
  Wt[2] = Wt[1] + 512 * 512;
  Wt[3] = Wt[2] + 512 * 512;
  unsigned char* Up[4];
  Up[0] = (unsigned char*)(Wt[3] + 512 * 512);
  Up[1] = Up[0] + 512 * 512;
  Up[2] = Up[1] + 512 * 512;
  Up[3] = Up[2] + 512 * 512;
  char* bankbase = w + SEQ_BYTES + WEIGHTS;
  bf16* BANK[4];
  for (int i = 0; i < 4; i++) BANK[i] = (bf16*)(bankbase + (size_t)i * XWB);

  {
    WConv wc{};
    UConv uc{};
    for (int i = 0; i < 4; i++) {
      wc.src[i] = Ws[i]; wc.dst[i] = Wt[i];
      wc.K[i] = (i == 0) ? 100 : 512;
      wc.Kp[i] = (i == 0) ? 128 : 512;
      uc.src[i] = Us[i]; uc.dst[i] = Up[i];
    }
    convert_weight_all<<<dim3(1024, 4), 256, 0, stream>>>(wc);
    convert_u_all<<<dim3(128, 4), 256, 0, stream>>>(uc);
  }

  if (wf) {
    // layer-wavefront: round r = gemm then rnn for tasks (l, c=r-l), bank per layer.
    for (int r = 0; r <= NC_ - 1 + L_ - 1; r++) {
      GemmTasks gt{};
      RnnTasks rt{};
      int n = 0;
      int lmin = r - (NC_ - 1); if (lmin < 0) lmin = 0;
      int lmax = r < L_ - 1 ? r : L_ - 1;
      for (int l = lmin; l <= lmax; l++) {
        int c = r - l;
        bf16* xb = BANK[l];
        gt.A[n] = SEQ + (size_t)c * TC_ * B_ * H_;
        gt.Bt[n] = Wt[l];
        gt.C[n] = xb;
        gt.kind[n] = (l == 0) ? 1 : 2;
        gt.t0[n] = c * TC_;
        rt.xwc[n] = xb;
        rt.U8[n] = Up[l];
        rt.bias[n] = bs[l];
        rt.t0[n] = c * TC_;
        rt.first[n] = (c == 0) ? 1 : 0;
        n++;
      }
      gemm_multi<<<n * 512, 256, 0, stream>>>(gt, tokens, emb);
      rnn_multi<<<n * 64, 1024, 0, stream>>>(rt, SEQ);
    }
  } else {
    // serial fallback: 2 banks
    for (int l = 0; l < L_; l++) {
      for (int c = 0; c < NC_; c++) {
        bf16* xb = BANK[c & 1];
        GemmTasks gt{};
        RnnTasks rt{};
        gt.A[0] = SEQ + (size_t)c * TC_ * B_ * H_;
        gt.Bt[0] = Wt[l];
        gt.C[0] = xb;
        gt.kind[0] = (l == 0) ? 1 : 2;
        gt.t0[0] = c * TC_;
        rt.xwc[0] = xb;
        rt.U8[0] = Up[l];
        rt.bias[0] = bs[l];
        rt.t0[0] = c * TC_;
        rt.first[0] = (c == 0) ? 1 : 0;
        gemm_multi<<<512, 256, 0, stream>>>(gt, tokens, emb);
        rnn_multi<<<64, 1024, 0, stream>>>(rt, SEQ);
      }
    }
  }

  head_kernel<<<B_ / 4, 256, 0, stream>>>(SEQ, Wo, bo, out);
}